// Round 11
// baseline (1322.173 us; speedup 1.0000x reference)
//
#include <hip/hip_runtime.h>
#include <math.h>

#define NN 65536
#define EE 1048576
#define GG 512
#define D  128

typedef float4 f4;

// ---------------------------------------------------------------- GEMM (fp32, 128x128 tile, 8x8 micro, split 4+4,
//   double-buffered LDS, single barrier per K-step, optional fused mean epilogue)
__global__ __launch_bounds__(256) void k_gemm(const float* __restrict__ A,
    const float* __restrict__ B, const float* __restrict__ bias,
    float* __restrict__ C, const float* __restrict__ mix_src, float* __restrict__ mix_dst,
    int M, int N, int K, int relu)
{
    __shared__ __align__(16) float As[2][16][132];
    __shared__ __align__(16) float Bs[2][16][132];
    int tid = threadIdx.x;
    int tx = tid & 15, ty = tid >> 4;
    int row0 = blockIdx.y * 128, col0 = blockIdx.x * 128;
    float acc[8][8];
#pragma unroll
    for (int i = 0; i < 8; ++i)
#pragma unroll
        for (int j = 0; j < 8; ++j) acc[i][j] = 0.f;
    int ar = tid >> 1, ac = (tid & 1) * 8;
    int br = tid >> 4, bc = (tid & 15) * 8;
    const float* aptr = A + (size_t)(row0 + ar) * K + ac;
    const float* bptr = B + (size_t)br * N + col0 + bc;

    f4 pa0 = *(const f4*)(aptr);
    f4 pa1 = *(const f4*)(aptr + 4);
    f4 pb0 = *(const f4*)(bptr);
    f4 pb1 = *(const f4*)(bptr + 4);
    As[0][ac + 0][ar] = pa0.x; As[0][ac + 1][ar] = pa0.y; As[0][ac + 2][ar] = pa0.z; As[0][ac + 3][ar] = pa0.w;
    As[0][ac + 4][ar] = pa1.x; As[0][ac + 5][ar] = pa1.y; As[0][ac + 6][ar] = pa1.z; As[0][ac + 7][ar] = pa1.w;
    *(f4*)&Bs[0][br][bc] = pb0; *(f4*)&Bs[0][br][bc + 4] = pb1;
    __syncthreads();

    int cur = 0;
    for (int k0 = 0; k0 < K; k0 += 16) {
        int last = (k0 + 16 >= K);
        if (!last) {
            pa0 = *(const f4*)(aptr + k0 + 16);
            pa1 = *(const f4*)(aptr + k0 + 16 + 4);
            pb0 = *(const f4*)(bptr + (size_t)(k0 + 16) * N);
            pb1 = *(const f4*)(bptr + (size_t)(k0 + 16) * N + 4);
        }
        const float (*Ac)[132] = As[cur];
        const float (*Bc)[132] = Bs[cur];
#pragma unroll
        for (int kk = 0; kk < 16; ++kk) {
            float a[8], b[8];
            *(f4*)&a[0] = *(const f4*)&Ac[kk][ty * 4];
            *(f4*)&a[4] = *(const f4*)&Ac[kk][64 + ty * 4];
            *(f4*)&b[0] = *(const f4*)&Bc[kk][tx * 4];
            *(f4*)&b[4] = *(const f4*)&Bc[kk][64 + tx * 4];
#pragma unroll
            for (int i = 0; i < 8; ++i)
#pragma unroll
                for (int j = 0; j < 8; ++j) acc[i][j] = fmaf(a[i], b[j], acc[i][j]);
        }
        if (!last) {
            int nxt = cur ^ 1;
            As[nxt][ac + 0][ar] = pa0.x; As[nxt][ac + 1][ar] = pa0.y; As[nxt][ac + 2][ar] = pa0.z; As[nxt][ac + 3][ar] = pa0.w;
            As[nxt][ac + 4][ar] = pa1.x; As[nxt][ac + 5][ar] = pa1.y; As[nxt][ac + 6][ar] = pa1.z; As[nxt][ac + 7][ar] = pa1.w;
            *(f4*)&Bs[nxt][br][bc] = pb0; *(f4*)&Bs[nxt][br][bc + 4] = pb1;
            __syncthreads();
            cur = nxt;
        }
    }

    f4 bia0 = *(const f4*)(bias + col0 + tx * 4);
    f4 bia1 = *(const f4*)(bias + col0 + 64 + tx * 4);
#pragma unroll
    for (int i = 0; i < 8; ++i) {
        int r = row0 + ((i < 4) ? (ty * 4 + i) : (64 + ty * 4 + i - 4));
        f4 v0, v1;
#pragma unroll
        for (int j = 0; j < 4; ++j) {
            float u0 = acc[i][j] + (&bia0.x)[j];
            float u1 = acc[i][j + 4] + (&bia1.x)[j];
            if (relu) { u0 = fmaxf(u0, 0.f); u1 = fmaxf(u1, 0.f); }
            (&v0.x)[j] = u0; (&v1.x)[j] = u1;
        }
        *(f4*)(C + (size_t)r * N + col0 + tx * 4) = v0;
        *(f4*)(C + (size_t)r * N + col0 + 64 + tx * 4) = v1;
        if (mix_dst) {
            f4 m0 = *(const f4*)(mix_src + (size_t)r * N + col0 + tx * 4);
            f4 m1 = *(const f4*)(mix_src + (size_t)r * N + col0 + 64 + tx * 4);
            f4 w0, w1;
#pragma unroll
            for (int j = 0; j < 4; ++j) {
                (&w0.x)[j] = 0.5f * ((&v0.x)[j] + (&m0.x)[j]);
                (&w1.x)[j] = 0.5f * ((&v1.x)[j] + (&m1.x)[j]);
            }
            *(f4*)(mix_dst + (size_t)r * N + col0 + tx * 4) = w0;
            *(f4*)(mix_dst + (size_t)r * N + col0 + 64 + tx * 4) = w1;
        }
    }
}

// ---------------------------------------------------------------- CSR build
__global__ __launch_bounds__(256) void k_hist(const int* __restrict__ Wr, int* __restrict__ cnt)
{
    int e = blockIdx.x * 256 + threadIdx.x;
    if (e < EE) atomicAdd(&cnt[Wr[e]], 1);
}

__global__ __launch_bounds__(256) void k_scan1(const int* __restrict__ cnt,
    int* __restrict__ excl, int* __restrict__ bsum)
{
    __shared__ int s[256];
    int b = blockIdx.x, t = threadIdx.x;
    int v = cnt[b * 256 + t];
    s[t] = v; __syncthreads();
    for (int o = 1; o < 256; o <<= 1) {
        int x = (t >= o) ? s[t - o] : 0;
        __syncthreads();
        s[t] += x;
        __syncthreads();
    }
    excl[b * 256 + t] = s[t] - v;
    if (t == 255) bsum[b] = s[255];
}

__global__ void k_scan2(const int* __restrict__ bsum, int* __restrict__ boff)
{
    __shared__ int s[256];
    int t = threadIdx.x;
    int v = bsum[t]; s[t] = v; __syncthreads();
    for (int o = 1; o < 256; o <<= 1) {
        int x = (t >= o) ? s[t - o] : 0;
        __syncthreads();
        s[t] += x;
        __syncthreads();
    }
    boff[t] = s[t] - v;
}

__global__ __launch_bounds__(256) void k_scan3(const int* __restrict__ excl, const int* __restrict__ boff,
    int* __restrict__ rowptr, int* __restrict__ cursor)
{
    int i = blockIdx.x * 256 + threadIdx.x;
    int v = excl[i] + boff[i >> 8];
    rowptr[i] = v; cursor[i] = v;
    if (i == 0) rowptr[NN] = EE;
}

__global__ __launch_bounds__(256) void k_scatter(const int* __restrict__ Wr, const int* __restrict__ Wc,
    const float* __restrict__ Wv, int* __restrict__ cursor, int* __restrict__ ecol, float* __restrict__ ev)
{
    int e = blockIdx.x * 256 + threadIdx.x;
    if (e >= EE) return;
    int r = Wr[e];
    int p = atomicAdd(&cursor[r], 1);
    ecol[p] = Wc[e]; ev[p] = Wv[e];
}

// ---------------------------------------------------------------- SpMM dual (CSR, wave/row, BOTH matrices per wave:
//   edge metadata read once, 8 gathers in flight for latency hiding)
// SAFETY (G16): Y0,Y1 disjoint from BOTH X0,X1. Per-matrix FMA order identical to single version.
__global__ __launch_bounds__(256) void k_spmm_dual(const int* __restrict__ rowptr,
    const int* __restrict__ ecol, const float* __restrict__ eval,
    const float* __restrict__ X0, float* __restrict__ Y0,
    const float* __restrict__ X1, float* __restrict__ Y1)
{
    int row = blockIdx.x * 4 + (threadIdx.x >> 6);
    int lane = threadIdx.x & 63;
    int s = rowptr[row], e = rowptr[row + 1];
    float a0 = 0.f, a1 = 0.f;   // matrix 0
    float b0 = 0.f, b1 = 0.f;   // matrix 1
    int i = s;
    for (; i + 4 <= e; i += 4) {
        int   c0 = ecol[i], c1 = ecol[i + 1], c2 = ecol[i + 2], c3 = ecol[i + 3];
        float w0 = eval[i], w1 = eval[i + 1], w2 = eval[i + 2], w3 = eval[i + 3];
        float2 xa0 = *(const float2*)(X0 + (size_t)c0 * D + lane * 2);
        float2 xa1 = *(const float2*)(X0 + (size_t)c1 * D + lane * 2);
        float2 xa2 = *(const float2*)(X0 + (size_t)c2 * D + lane * 2);
        float2 xa3 = *(const float2*)(X0 + (size_t)c3 * D + lane * 2);
        float2 xb0 = *(const float2*)(X1 + (size_t)c0 * D + lane * 2);
        float2 xb1 = *(const float2*)(X1 + (size_t)c1 * D + lane * 2);
        float2 xb2 = *(const float2*)(X1 + (size_t)c2 * D + lane * 2);
        float2 xb3 = *(const float2*)(X1 + (size_t)c3 * D + lane * 2);
        a0 = fmaf(w0, xa0.x, a0); a1 = fmaf(w0, xa0.y, a1);
        a0 = fmaf(w1, xa1.x, a0); a1 = fmaf(w1, xa1.y, a1);
        a0 = fmaf(w2, xa2.x, a0); a1 = fmaf(w2, xa2.y, a1);
        a0 = fmaf(w3, xa3.x, a0); a1 = fmaf(w3, xa3.y, a1);
        b0 = fmaf(w0, xb0.x, b0); b1 = fmaf(w0, xb0.y, b1);
        b0 = fmaf(w1, xb1.x, b0); b1 = fmaf(w1, xb1.y, b1);
        b0 = fmaf(w2, xb2.x, b0); b1 = fmaf(w2, xb2.y, b1);
        b0 = fmaf(w3, xb3.x, b0); b1 = fmaf(w3, xb3.y, b1);
    }
    for (; i < e; ++i) {
        int cc = ecol[i];
        float w = eval[i];
        float2 xa = *(const float2*)(X0 + (size_t)cc * D + lane * 2);
        float2 xb = *(const float2*)(X1 + (size_t)cc * D + lane * 2);
        a0 = fmaf(w, xa.x, a0); a1 = fmaf(w, xa.y, a1);
        b0 = fmaf(w, xb.x, b0); b1 = fmaf(w, xb.y, b1);
    }
    *(float2*)(Y0 + (size_t)row * D + lane * 2) = make_float2(a0, a1);
    *(float2*)(Y1 + (size_t)row * D + lane * 2) = make_float2(b0, b1);
}

// ---------------------------------------------------------------- BN stats (dual matrix read-only fuse, f64 partials)
__global__ __launch_bounds__(128) void k_bnstats2(const float* __restrict__ X0, const float* __restrict__ X1,
    double* __restrict__ psum, double* __restrict__ pssq)
{
    const float* __restrict__ X = blockIdx.y ? X1 : X0;
    int d = threadIdx.x;
    int r0 = blockIdx.x * 128;
    double s = 0.0, q = 0.0;
#pragma unroll 4
    for (int r = r0; r < r0 + 128; ++r) {
        double v = (double)X[(size_t)r * D + d];
        s += v; q = fma(v, v, q);
    }
    psum[blockIdx.y * 65536 + blockIdx.x * 128 + d] = s;
    pssq[blockIdx.y * 65536 + blockIdx.x * 128 + d] = q;
}

__global__ void k_bnfin(const double* __restrict__ psum, const double* __restrict__ pssq,
    const float* __restrict__ gamma, const float* __restrict__ beta,
    double* __restrict__ a, double* __restrict__ c, int nb, int layer)
{
    int t = threadIdx.x;
    if (t >= nb * 128) return;
    int blk = t >> 7, d = t & 127;
    const double* ps = psum + blk * 65536;
    const double* pq = pssq + blk * 65536;
    double s = 0.0, q = 0.0;
    for (int j = 0; j < 512; ++j) { s += ps[j * 128 + d]; q += pq[j * 128 + d]; }
    double m = s * (1.0 / 65536.0);
    double v = q * (1.0 / 65536.0) - m * m;
    double aa = (double)gamma[layer * 128 + d] / sqrt(v + 1e-5);
    a[t] = aa;
    c[t] = (double)beta[layer * 128 + d] - m * aa;
}

// ---------------------------------------------------------------- elementwise (f32, f4)
// o may alias p1 (same-index elementwise) -> no __restrict__ on p1/o.
__global__ __launch_bounds__(256) void k_hidden(const f4* __restrict__ p0, const f4* p1,
    const double* __restrict__ a, const double* __restrict__ c, f4* o)
{
    int i = blockIdx.x * 256 + threadIdx.x;
    int d4 = (i & 31) * 4;
    f4 x = p0[i], y = p1[i];
    f4 r;
#pragma unroll
    for (int j = 0; j < 4; ++j) {
        float a0 = (float)a[d4 + j], c0 = (float)c[d4 + j];
        float a1 = (float)a[128 + d4 + j], c1 = (float)c[128 + d4 + j];
        float xv = (&x.x)[j], yv = (&y.x)[j];
        (&r.x)[j] = 0.5f * (fmaxf(fmaf(xv, a0, c0), 0.f) + fmaxf(fmaf(yv, a1, c1), 0.f));
    }
    o[i] = r;
}

__global__ __launch_bounds__(256) void k_bnapply(f4* __restrict__ H,
    const double* __restrict__ a, const double* __restrict__ c)
{
    int i = blockIdx.x * 256 + threadIdx.x;
    int d4 = (i & 31) * 4;
    f4 x = H[i];
#pragma unroll
    for (int j = 0; j < 4; ++j) {
        float a0 = (float)a[d4 + j], c0 = (float)c[d4 + j];
        (&x.x)[j] = fmaxf(fmaf((&x.x)[j], a0, c0), 0.f);
    }
    H[i] = x;
}

// ---------------------------------------------------------------- concat MLP (f32, 4 elems/thread,
//   weights read via WAVE-UNIFORM global loads -> scalar s_load path, zero LDS traffic)
__global__ __launch_bounds__(256) void k_concat(const f4* __restrict__ h0, const f4* __restrict__ h1,
    const f4* __restrict__ h2, const f4* __restrict__ h3,
    const float* __restrict__ w1, const float* __restrict__ b1,
    const float* __restrict__ w2, const float* __restrict__ b2,
    f4* __restrict__ Hpre)
{
    int i = blockIdx.x * 256 + threadIdx.x;  // f4 units, < N*D/4
    f4 x0 = h0[i], x1 = h1[i], x2 = h2[i], x3 = h3[i];
    float bb2 = b2[0];
    float acc0 = bb2, acc1 = bb2, acc2 = bb2, acc3 = bb2;
    for (int h4 = 0; h4 < D; h4 += 4) {
        f4 cw0 = *(const f4*)&w1[h4];          // uniform index -> s_load_dwordx4
        f4 cw1 = *(const f4*)&w1[128 + h4];
        f4 cw2 = *(const f4*)&w1[256 + h4];
        f4 cw3 = *(const f4*)&w1[384 + h4];
        f4 cbb = *(const f4*)&b1[h4];
        f4 cvv = *(const f4*)&w2[h4];
#pragma unroll
        for (int j = 0; j < 4; ++j) {
            float w0 = (&cw0.x)[j], ww1 = (&cw1.x)[j], ww2 = (&cw2.x)[j], w3 = (&cw3.x)[j];
            float bb = (&cbb.x)[j], vv = (&cvv.x)[j];
            float t0 = fmaf(x3.x, w3, fmaf(x2.x, ww2, fmaf(x1.x, ww1, fmaf(x0.x, w0, bb))));
            float t1 = fmaf(x3.y, w3, fmaf(x2.y, ww2, fmaf(x1.y, ww1, fmaf(x0.y, w0, bb))));
            float t2 = fmaf(x3.z, w3, fmaf(x2.z, ww2, fmaf(x1.z, ww1, fmaf(x0.z, w0, bb))));
            float t3 = fmaf(x3.w, w3, fmaf(x2.w, ww2, fmaf(x1.w, ww1, fmaf(x0.w, w0, bb))));
            acc0 = fmaf(fmaxf(t0, 0.f), vv, acc0);
            acc1 = fmaf(fmaxf(t1, 0.f), vv, acc1);
            acc2 = fmaf(fmaxf(t2, 0.f), vv, acc2);
            acc3 = fmaf(fmaxf(t3, 0.f), vv, acc3);
        }
    }
    f4 r; r.x = acc0; r.y = acc1; r.z = acc2; r.w = acc3;
    Hpre[i] = r;
}

// ---------------------------------------------------------------- S = softmax(hid @ w2 + b2) (f32)
__global__ __launch_bounds__(256) void k_s(const float* __restrict__ hid,
    const float* __restrict__ w2, const float* __restrict__ b2, float* __restrict__ S)
{
    int n = blockIdx.x * 256 + threadIdx.x;
    if (n >= NN) return;
    const float* hr = hid + (size_t)n * D;
    float s[10];
#pragma unroll
    for (int k = 0; k < 10; ++k) s[k] = b2[k];
    for (int h = 0; h < D; h += 4) {
        f4 hv = *(const f4*)(hr + h);
#pragma unroll
        for (int k = 0; k < 10; ++k) {
            s[k] = fmaf(hv.x, w2[(h + 0) * 10 + k], s[k]);
            s[k] = fmaf(hv.y, w2[(h + 1) * 10 + k], s[k]);
            s[k] = fmaf(hv.z, w2[(h + 2) * 10 + k], s[k]);
            s[k] = fmaf(hv.w, w2[(h + 3) * 10 + k], s[k]);
        }
    }
    float m = s[0];
#pragma unroll
    for (int k = 1; k < 10; ++k) m = fmaxf(m, s[k]);
    float e[10], sum = 0.f;
#pragma unroll
    for (int k = 0; k < 10; ++k) { e[k] = expf(s[k] - m); sum += e[k]; }
    float inv = 1.f / sum;
#pragma unroll
    for (int k = 0; k < 10; ++k) S[(size_t)n * 10 + k] = e[k] * inv;
}

// ---------------------------------------------------------------- E_all (f32 in, f64 accum, dual store)
__global__ __launch_bounds__(256) void k_eall(const float* __restrict__ S, const float* __restrict__ H,
    const int* __restrict__ off, float* __restrict__ Eo, double* __restrict__ E64)
{
    int g = blockIdx.x;
    int d = threadIdx.x & 127;
    int half = threadIdx.x >> 7;
    double acc[5] = {0.0, 0.0, 0.0, 0.0, 0.0};
    int s0 = off[g], s1 = off[g + 1];
    for (int n = s0; n < s1; ++n) {
        double hv = (double)H[(size_t)n * D + d];
#pragma unroll
        for (int j = 0; j < 5; ++j) acc[j] = fma((double)S[(size_t)n * 10 + half * 5 + j], hv, acc[j]);
    }
#pragma unroll
    for (int j = 0; j < 5; ++j) {
        size_t o = (size_t)g * 1280 + (half * 5 + j) * D + d;
        Eo[o] = (float)acc[j];
        E64[o] = acc[j];
    }
}

// ---------------------------------------------------------------- graph offsets
__global__ void k_off(const int* __restrict__ gi, int* __restrict__ off)
{
    int g = blockIdx.x * 256 + threadIdx.x;
    if (g > GG) return;
    int lo = 0, hi = NN;
    while (lo < hi) { int mid = (lo + hi) >> 1; if (gi[mid] < g) lo = mid + 1; else hi = mid; }
    off[g] = lo;
}

// ---------------------------------------------------------------- corr
__global__ void k_corr(const float* __restrict__ ci, const float* __restrict__ ca, float* __restrict__ corr)
{
    int t = threadIdx.x;
    if (t >= 160) return;
    int r = t / 16, c = t % 16;
    double m = -1e300;
    for (int i = 0; i < 10; ++i) m = fmax(m, (double)ci[i * 16 + c]);
    double s = 0.0;
    for (int i = 0; i < 10; ++i) s += exp((double)ci[i * 16 + c] - m);
    double vi = exp((double)ci[r * 16 + c] - m) / s;
    double m2 = -1e300;
    for (int j = 0; j < 16; ++j) m2 = fmax(m2, (double)ca[r * 16 + j]);
    double s2 = 0.0;
    for (int j = 0; j < 16; ++j) s2 += exp((double)ca[r * 16 + j] - m2);
    double va = exp((double)ca[r * 16 + c] - m2) / s2;
    corr[t] = (float)(vi * va);
}

// ---------------------------------------------------------------- JAX threefry gumbel — PARTITIONABLE (verified)
__device__ __forceinline__ unsigned tf_rotl(unsigned x, unsigned n) { return (x << n) | (x >> (32u - n)); }

__global__ void k_gumbel(double* __restrict__ out)
{
    int i = blockIdx.x * 256 + threadIdx.x;
    if (i >= 5120) return;
    unsigned x0 = 0u;
    unsigned x1 = (unsigned)i;
    const unsigned ks0 = 0u, ks1 = 42u;
    const unsigned ks2 = 0x1BD11BDAu ^ ks0 ^ ks1;
    x0 += ks0; x1 += ks1;
#define TF_ROUND(rr) { x0 += x1; x1 = tf_rotl(x1, rr); x1 ^= x0; }
    TF_ROUND(13) TF_ROUND(15) TF_ROUND(26) TF_ROUND(6)
    x0 += ks1; x1 += ks2 + 1u;
    TF_ROUND(17) TF_ROUND(29) TF_ROUND(16) TF_ROUND(24)
    x0 += ks2; x1 += ks0 + 2u;
    TF_ROUND(13) TF_ROUND(15) TF_ROUND(26) TF_ROUND(6)
    x0 += ks0; x1 += ks1 + 3u;
    TF_ROUND(17) TF_ROUND(29) TF_ROUND(16) TF_ROUND(24)
    x0 += ks1; x1 += ks2 + 4u;
    TF_ROUND(13) TF_ROUND(15) TF_ROUND(26) TF_ROUND(6)
    x0 += ks2; x1 += ks0 + 5u;
#undef TF_ROUND
    unsigned bits = x0 ^ x1;
    unsigned fb = (bits >> 9) | 0x3f800000u;
    float f = __uint_as_float(fb) - 1.0f;
    const float tinyf = 1.1754943508222875e-38f;
    float u32v = fmaxf(tinyf, f * (1.0f - tinyf) + tinyf);
    out[i] = -log(-log((double)u32v));
}

// ---------------------------------------------------------------- pred1 + sampling (f64)
__global__ __launch_bounds__(64) void k_pred1(const double* __restrict__ E64, const float* __restrict__ fw,
    const float* __restrict__ fb, const double* __restrict__ gum, const int* __restrict__ tgt,
    const float* __restrict__ corr, float* __restrict__ pred1, float* __restrict__ ind,
    float* __restrict__ cmask)
{
    int g = blockIdx.x;
    int l = threadIdx.x;
    double acc[10];
#pragma unroll
    for (int c = 0; c < 10; ++c) acc[c] = 0.0;
    for (int i = l; i < 1280; i += 64) {
        double e = E64[(size_t)g * 1280 + i];
#pragma unroll
        for (int c = 0; c < 10; ++c) acc[c] = fma(e, (double)fw[i * 10 + c], acc[c]);
    }
#pragma unroll
    for (int c = 0; c < 10; ++c) {
        double v = acc[c];
        for (int o = 32; o > 0; o >>= 1) v += __shfl_down(v, o, 64);
        acc[c] = v;
    }
    if (l == 0) {
        double best = -1e300; int bi = 0;
        for (int c = 0; c < 10; ++c) {
            double p = acc[c] + (double)fb[c];
            pred1[g * 10 + c] = (float)p;
            double y = p + gum[g * 10 + c];
            if (y > best) { best = y; bi = c; }
        }
        ind[g] = (bi == tgt[g]) ? 1.f : 0.f;
        for (int f = 0; f < 16; ++f) cmask[g * 16 + f] = corr[bi * 16 + f];
    }
}

// ---------------------------------------------------------------- Q + feature_mask (f32)
__global__ __launch_bounds__(128) void k_q(const float* __restrict__ Eo, const float* __restrict__ w1,
    const float* __restrict__ b1, const float* __restrict__ w2, const float* __restrict__ b2,
    const float* __restrict__ cmask, float* __restrict__ Q, float* __restrict__ fm)
{
    int gk = blockIdx.x;
    int g = gk / 10;
    int h = threadIdx.x;
    __shared__ float e[128];
    __shared__ float hh[128];
    __shared__ float qv[16];
    __shared__ float pr[16];
    e[h] = Eo[(size_t)gk * D + h];
    __syncthreads();
    float acc = b1[h];
#pragma unroll 8
    for (int d = 0; d < D; ++d) acc = fmaf(e[d], w1[d * D + h], acc);
    hh[h] = fmaxf(acc, 0.f);
    __syncthreads();
    if (h < 16) {
        float s = b2[h];
        for (int d = 0; d < D; ++d) s = fmaf(hh[d], w2[d * 16 + h], s);
        qv[h] = s;
    }
    __syncthreads();
    if (h < 16) {
        float m = qv[0];
        for (int f = 1; f < 16; ++f) m = fmaxf(m, qv[f]);
        pr[h] = expf(qv[h] - m);
    }
    __syncthreads();
    if (h < 16) {
        float s = 0.f;
        for (int f = 0; f < 16; ++f) s += pr[f];
        float q = pr[h] / s;
        Q[(size_t)gk * 16 + h] = q;
        qv[h] = q * cmask[g * 16 + h];
    }
    __syncthreads();
    if (h == 0) {
        float s = 0.f;
        for (int f = 0; f < 16; ++f) s += qv[f];
        fm[gk] = s;
    }
}

// ---------------------------------------------------------------- pred2 (f64 accum from E64)
__global__ __launch_bounds__(64) void k_pred2(const double* __restrict__ E64, const float* __restrict__ fw,
    const float* __restrict__ fb, const float* __restrict__ fm, float* __restrict__ pred2)
{
    int g = blockIdx.x;
    int l = threadIdx.x;
    double acc[10];
#pragma unroll
    for (int c = 0; c < 10; ++c) acc[c] = 0.0;
    for (int i = l; i < 1280; i += 64) {
        int k = i >> 7;
        double e = E64[(size_t)g * 1280 + i] * (double)fm[g * 10 + k];
#pragma unroll
        for (int c = 0; c < 10; ++c) acc[c] = fma(e, (double)fw[i * 10 + c], acc[c]);
    }
#pragma unroll
    for (int c = 0; c < 10; ++c) {
        double v = acc[c];
        for (int o = 32; o > 0; o >>= 1) v += __shfl_down(v, o, 64);
        acc[c] = v;
    }
    if (l == 0)
        for (int c = 0; c < 10; ++c) pred2[g * 10 + c] = (float)(acc[c] + (double)fb[c]);
}

// ================================================================ host
extern "C" void kernel_launch(void* const* d_in, const int* in_sizes, int n_in,
                              void* d_out, int out_size, void* d_ws, size_t ws_size,
                              hipStream_t stream)
{
    const float* features = (const float*)d_in[0];
    const int*   W_row    = (const int*)d_in[1];
    const int*   W_col    = (const int*)d_in[2];
    const float* W_vals   = (const float*)d_in[3];
    const int*   gi       = (const int*)d_in[4];
    const int*   targets  = (const int*)d_in[5];
    const float* enc_w1   = (const float*)d_in[6];
    const float* enc_b1   = (const float*)d_in[7];
    const float* enc_w2   = (const float*)d_in[8];
    const float* enc_b2   = (const float*)d_in[9];
    const float* bn_gamma = (const float*)d_in[10];
    const float* bn_beta  = (const float*)d_in[11];
    const float* concat_w1= (const float*)d_in[12];
    const float* concat_b1= (const float*)d_in[13];
    const float* concat_w2= (const float*)d_in[14];
    const float* concat_b2= (const float*)d_in[15];
    const float* smlp_w1  = (const float*)d_in[16];
    const float* smlp_b1  = (const float*)d_in[17];
    const float* smlp_w2  = (const float*)d_in[18];
    const float* smlp_b2  = (const float*)d_in[19];
    const float* proto_w1 = (const float*)d_in[20];
    const float* proto_b1 = (const float*)d_in[21];
    const float* proto_w2 = (const float*)d_in[22];
    const float* proto_b2 = (const float*)d_in[23];
    const float* final_w  = (const float*)d_in[24];
    const float* final_b  = (const float*)d_in[25];
    const float* corr_i   = (const float*)d_in[26];
    const float* corr_a   = (const float*)d_in[27];

    float* out = (float*)d_out;
    float* o_pred1 = out + 0;
    float* o_pred2 = out + 5120;
    float* o_S     = out + 10240;
    float* o_H     = out + 665600;
    float* o_ind   = out + 9054208;
    float* o_E     = out + 9054720;
    float* o_Q     = out + 9710080;

    // ---------------- workspace arena (total ~240 MiB — proven fit; do NOT grow: round-8 crash)
    char* base = (char*)d_ws;
    size_t off = 0;
    auto alloc = [&](size_t n) -> char* {
        char* r = base + off;
        off = (off + n + 255) & ~(size_t)255;
        return r;
    };
    int*    d_off   = (int*)alloc(513 * 4);
    double* d_a     = (double*)alloc(256 * 8);
    double* d_c     = (double*)alloc(256 * 8);
    double* d_gum   = (double*)alloc(5120 * 8);
    float*  d_corr  = (float*)alloc(160 * 4);
    float*  d_cmask = (float*)alloc(512 * 16 * 4);
    float*  d_fm    = (float*)alloc(5120 * 4);
    double* psum    = (double*)alloc(2 * 512 * 128 * 8);
    double* pssq    = (double*)alloc(2 * 512 * 128 * 8);
    int*    cnt     = (int*)alloc((size_t)NN * 4);
    int*    excl    = (int*)alloc((size_t)NN * 4);
    int*    bsum    = (int*)alloc(256 * 4);
    int*    boff    = (int*)alloc(256 * 4);
    int*    rowptr  = (int*)alloc((size_t)(NN + 1) * 4);
    int*    cursor  = (int*)alloc((size_t)NN * 4);
    int*    ecol    = (int*)alloc((size_t)EE * 4);
    float*  evalv   = (float*)alloc((size_t)EE * 4);
    double* E64     = (double*)alloc((size_t)GG * 1280 * 8);

    const size_t SZ = (size_t)NN * D * 4;   // 32 MiB per f32 tensor
    float* rot0 = (float*)alloc(SZ);
    float* rot1 = (float*)alloc(SZ);
    float* rot2 = (float*)alloc(SZ);
    float* h0   = (float*)alloc(SZ);
    float* h1   = (float*)alloc(SZ);
    float* h2   = (float*)alloc(SZ);
    float* h3   = (float*)alloc(SZ);
    float* Tenc = h2;        // N x 256 f32 spans h2+h3 (dead after encoder)
    float* hid2 = rot0;      // smlp hidden reuses rot region after prop loop

    // ---------------- small precomputations
    k_off   <<<3, 256, 0, stream>>>(gi, d_off);
    k_corr  <<<1, 256, 0, stream>>>(corr_i, corr_a, d_corr);
    k_gumbel<<<20, 256, 0, stream>>>(d_gum);

    // ---------------- CSR build
    hipMemsetAsync(cnt, 0, (size_t)NN * 4, stream);
    k_hist   <<<EE / 256, 256, 0, stream>>>(W_row, cnt);
    k_scan1  <<<256, 256, 0, stream>>>(cnt, excl, bsum);
    k_scan2  <<<1, 256, 0, stream>>>(bsum, boff);
    k_scan3  <<<256, 256, 0, stream>>>(excl, boff, rowptr, cursor);
    k_scatter<<<EE / 256, 256, 0, stream>>>(W_row, W_col, W_vals, cursor, ecol, evalv);

    // ---------------- encoder (f32); 4th GEMM fuses hidden_rep[0] = 0.5*(rot0+rot1) -> h0
    k_gemm<<<dim3(2, 512), 256, 0, stream>>>(features, enc_w1,             enc_b1,       Tenc, nullptr, nullptr, NN, 256, 128, 1);
    k_gemm<<<dim3(1, 512), 256, 0, stream>>>(Tenc,     enc_w2,             enc_b2,       rot0, nullptr, nullptr, NN, 128, 256, 0);
    k_gemm<<<dim3(2, 512), 256, 0, stream>>>(features, enc_w1 + 128 * 256, enc_b1 + 256, Tenc, nullptr, nullptr, NN, 256, 128, 1);
    k_gemm<<<dim3(1, 512), 256, 0, stream>>>(Tenc,     enc_w2 + 256 * 128, enc_b2 + 128, rot1, rot0, h0,         NN, 128, 256, 0);

    // ---------------- propagation loop: per-wave dual SpMM, zero extra memory.
    // p=0: (rot0,rot1)->(rot2,h2), hidden->h1
    // p=1: (rot2,h2)->(rot0,rot1), hidden->h2   (h2 read by spmm BEFORE hidden overwrites it)
    // p=2: (rot0,rot1)->(rot2,h3), hidden(rot2,h3)->h3 (in-place elementwise, same-index, safe)
    {
        float* hbuf[4] = { h0, h1, h2, h3 };
        float* curA = rot0; float* curB = rot1;
        float* nxtA[3] = { rot2, rot0, rot2 };
        float* nxtB[3] = { h2,   rot1, h3   };
        for (int p = 0; p < 3; ++p) {
            float* nA = nxtA[p];
            float* nB = nxtB[p];
            k_spmm_dual<<<NN / 4, 256, 0, stream>>>(rowptr, ecol, evalv, curA, nA, curB, nB);
            k_bnstats2<<<dim3(512, 2), 128, 0, stream>>>(nA, nB, psum, pssq);
            k_bnfin<<<1, 256, 0, stream>>>(psum, pssq, bn_gamma, bn_beta, d_a, d_c, 2, p);
            k_hidden<<<8192, 256, 0, stream>>>((const f4*)nA, (const f4*)nB, d_a, d_c, (f4*)hbuf[1 + p]);
            curA = nA; curB = nB;
        }
    }

    // ---------------- concat MLP -> o_H, BN+relu in place
    k_concat<<<8192, 256, 0, stream>>>((const f4*)h0, (const f4*)h1, (const f4*)h2, (const f4*)h3,
                                       concat_w1, concat_b1, concat_w2, concat_b2, (f4*)o_H);
    k_bnstats2<<<dim3(512, 1), 128, 0, stream>>>(o_H, o_H, psum, pssq);
    k_bnfin<<<1, 256, 0, stream>>>(psum, pssq, bn_gamma, bn_beta, d_a, d_c, 1, 3);
    k_bnapply<<<8192, 256, 0, stream>>>((f4*)o_H, d_a, d_c);

    // ---------------- S_all
    k_gemm<<<dim3(1, 512), 256, 0, stream>>>(o_H, smlp_w1, smlp_b1, hid2, nullptr, nullptr, NN, 128, 128, 1);
    k_s<<<256, 256, 0, stream>>>(hid2, smlp_w2, smlp_b2, o_S);

    // ---------------- E_all, heads
    k_eall <<<512, 256, 0, stream>>>(o_S, o_H, d_off, o_E, E64);
    k_pred1<<<512, 64, 0, stream>>>(E64, final_w, final_b, d_gum, targets, d_corr,
                                    o_pred1, o_ind, d_cmask);
    k_q    <<<5120, 128, 0, stream>>>(o_E, proto_w1, proto_b1, proto_w2, proto_b2,
                                      d_cmask, o_Q, d_fm);
    k_pred2<<<512, 64, 0, stream>>>(E64, final_w, final_b, d_fm, o_pred2);

    (void)in_sizes; (void)n_in; (void)out_size; (void)ws_size;
}

// Round 12
// 1321.039 us; speedup vs baseline: 1.0009x; 1.0009x over previous
//
#include <hip/hip_runtime.h>
#include <math.h>

#define NN 65536
#define EE 1048576
#define GG 512
#define D  128

typedef float4 f4;

// ---------------------------------------------------------------- GEMM (fp32, 128x128 tile, 8x8 micro, split 4+4,
//   double-buffered LDS, single barrier per K-step, optional fused mean epilogue)
__global__ __launch_bounds__(256) void k_gemm(const float* __restrict__ A,
    const float* __restrict__ B, const float* __restrict__ bias,
    float* __restrict__ C, const float* __restrict__ mix_src, float* __restrict__ mix_dst,
    int M, int N, int K, int relu)
{
    __shared__ __align__(16) float As[2][16][132];
    __shared__ __align__(16) float Bs[2][16][132];
    int tid = threadIdx.x;
    int tx = tid & 15, ty = tid >> 4;
    int row0 = blockIdx.y * 128, col0 = blockIdx.x * 128;
    float acc[8][8];
#pragma unroll
    for (int i = 0; i < 8; ++i)
#pragma unroll
        for (int j = 0; j < 8; ++j) acc[i][j] = 0.f;
    int ar = tid >> 1, ac = (tid & 1) * 8;
    int br = tid >> 4, bc = (tid & 15) * 8;
    const float* aptr = A + (size_t)(row0 + ar) * K + ac;
    const float* bptr = B + (size_t)br * N + col0 + bc;

    f4 pa0 = *(const f4*)(aptr);
    f4 pa1 = *(const f4*)(aptr + 4);
    f4 pb0 = *(const f4*)(bptr);
    f4 pb1 = *(const f4*)(bptr + 4);
    As[0][ac + 0][ar] = pa0.x; As[0][ac + 1][ar] = pa0.y; As[0][ac + 2][ar] = pa0.z; As[0][ac + 3][ar] = pa0.w;
    As[0][ac + 4][ar] = pa1.x; As[0][ac + 5][ar] = pa1.y; As[0][ac + 6][ar] = pa1.z; As[0][ac + 7][ar] = pa1.w;
    *(f4*)&Bs[0][br][bc] = pb0; *(f4*)&Bs[0][br][bc + 4] = pb1;
    __syncthreads();

    int cur = 0;
    for (int k0 = 0; k0 < K; k0 += 16) {
        int last = (k0 + 16 >= K);
        if (!last) {
            pa0 = *(const f4*)(aptr + k0 + 16);
            pa1 = *(const f4*)(aptr + k0 + 16 + 4);
            pb0 = *(const f4*)(bptr + (size_t)(k0 + 16) * N);
            pb1 = *(const f4*)(bptr + (size_t)(k0 + 16) * N + 4);
        }
        const float (*Ac)[132] = As[cur];
        const float (*Bc)[132] = Bs[cur];
#pragma unroll
        for (int kk = 0; kk < 16; ++kk) {
            float a[8], b[8];
            *(f4*)&a[0] = *(const f4*)&Ac[kk][ty * 4];
            *(f4*)&a[4] = *(const f4*)&Ac[kk][64 + ty * 4];
            *(f4*)&b[0] = *(const f4*)&Bc[kk][tx * 4];
            *(f4*)&b[4] = *(const f4*)&Bc[kk][64 + tx * 4];
#pragma unroll
            for (int i = 0; i < 8; ++i)
#pragma unroll
                for (int j = 0; j < 8; ++j) acc[i][j] = fmaf(a[i], b[j], acc[i][j]);
        }
        if (!last) {
            int nxt = cur ^ 1;
            As[nxt][ac + 0][ar] = pa0.x; As[nxt][ac + 1][ar] = pa0.y; As[nxt][ac + 2][ar] = pa0.z; As[nxt][ac + 3][ar] = pa0.w;
            As[nxt][ac + 4][ar] = pa1.x; As[nxt][ac + 5][ar] = pa1.y; As[nxt][ac + 6][ar] = pa1.z; As[nxt][ac + 7][ar] = pa1.w;
            *(f4*)&Bs[nxt][br][bc] = pb0; *(f4*)&Bs[nxt][br][bc + 4] = pb1;
            __syncthreads();
            cur = nxt;
        }
    }

    f4 bia0 = *(const f4*)(bias + col0 + tx * 4);
    f4 bia1 = *(const f4*)(bias + col0 + 64 + tx * 4);
#pragma unroll
    for (int i = 0; i < 8; ++i) {
        int r = row0 + ((i < 4) ? (ty * 4 + i) : (64 + ty * 4 + i - 4));
        f4 v0, v1;
#pragma unroll
        for (int j = 0; j < 4; ++j) {
            float u0 = acc[i][j] + (&bia0.x)[j];
            float u1 = acc[i][j + 4] + (&bia1.x)[j];
            if (relu) { u0 = fmaxf(u0, 0.f); u1 = fmaxf(u1, 0.f); }
            (&v0.x)[j] = u0; (&v1.x)[j] = u1;
        }
        *(f4*)(C + (size_t)r * N + col0 + tx * 4) = v0;
        *(f4*)(C + (size_t)r * N + col0 + 64 + tx * 4) = v1;
        if (mix_dst) {
            f4 m0 = *(const f4*)(mix_src + (size_t)r * N + col0 + tx * 4);
            f4 m1 = *(const f4*)(mix_src + (size_t)r * N + col0 + 64 + tx * 4);
            f4 w0, w1;
#pragma unroll
            for (int j = 0; j < 4; ++j) {
                (&w0.x)[j] = 0.5f * ((&v0.x)[j] + (&m0.x)[j]);
                (&w1.x)[j] = 0.5f * ((&v1.x)[j] + (&m1.x)[j]);
            }
            *(f4*)(mix_dst + (size_t)r * N + col0 + tx * 4) = w0;
            *(f4*)(mix_dst + (size_t)r * N + col0 + 64 + tx * 4) = w1;
        }
    }
}

// ---------------------------------------------------------------- CSR build
__global__ __launch_bounds__(256) void k_hist(const int* __restrict__ Wr, int* __restrict__ cnt)
{
    int e = blockIdx.x * 256 + threadIdx.x;
    if (e < EE) atomicAdd(&cnt[Wr[e]], 1);
}

__global__ __launch_bounds__(256) void k_scan1(const int* __restrict__ cnt,
    int* __restrict__ excl, int* __restrict__ bsum)
{
    __shared__ int s[256];
    int b = blockIdx.x, t = threadIdx.x;
    int v = cnt[b * 256 + t];
    s[t] = v; __syncthreads();
    for (int o = 1; o < 256; o <<= 1) {
        int x = (t >= o) ? s[t - o] : 0;
        __syncthreads();
        s[t] += x;
        __syncthreads();
    }
    excl[b * 256 + t] = s[t] - v;
    if (t == 255) bsum[b] = s[255];
}

__global__ void k_scan2(const int* __restrict__ bsum, int* __restrict__ boff)
{
    __shared__ int s[256];
    int t = threadIdx.x;
    int v = bsum[t]; s[t] = v; __syncthreads();
    for (int o = 1; o < 256; o <<= 1) {
        int x = (t >= o) ? s[t - o] : 0;
        __syncthreads();
        s[t] += x;
        __syncthreads();
    }
    boff[t] = s[t] - v;
}

__global__ __launch_bounds__(256) void k_scan3(const int* __restrict__ excl, const int* __restrict__ boff,
    int* __restrict__ rowptr, int* __restrict__ cursor)
{
    int i = blockIdx.x * 256 + threadIdx.x;
    int v = excl[i] + boff[i >> 8];
    rowptr[i] = v; cursor[i] = v;
    if (i == 0) rowptr[NN] = EE;
}

__global__ __launch_bounds__(256) void k_scatter(const int* __restrict__ Wr, const int* __restrict__ Wc,
    const float* __restrict__ Wv, int* __restrict__ cursor, int* __restrict__ ecol, float* __restrict__ ev)
{
    int e = blockIdx.x * 256 + threadIdx.x;
    if (e >= EE) return;
    int r = Wr[e];
    int p = atomicAdd(&cursor[r], 1);
    ecol[p] = Wc[e]; ev[p] = Wv[e];
}

// ---------------------------------------------------------------- SpMM dual (CSR, wave/row, BOTH matrices per wave:
//   edge metadata read once, 8 gathers in flight) — verified win (round 11)
// SAFETY (G16): Y0,Y1 disjoint from BOTH X0,X1. Per-matrix FMA order identical to single version.
__global__ __launch_bounds__(256) void k_spmm_dual(const int* __restrict__ rowptr,
    const int* __restrict__ ecol, const float* __restrict__ eval,
    const float* __restrict__ X0, float* __restrict__ Y0,
    const float* __restrict__ X1, float* __restrict__ Y1)
{
    int row = blockIdx.x * 4 + (threadIdx.x >> 6);
    int lane = threadIdx.x & 63;
    int s = rowptr[row], e = rowptr[row + 1];
    float a0 = 0.f, a1 = 0.f;   // matrix 0
    float b0 = 0.f, b1 = 0.f;   // matrix 1
    int i = s;
    for (; i + 4 <= e; i += 4) {
        int   c0 = ecol[i], c1 = ecol[i + 1], c2 = ecol[i + 2], c3 = ecol[i + 3];
        float w0 = eval[i], w1 = eval[i + 1], w2 = eval[i + 2], w3 = eval[i + 3];
        float2 xa0 = *(const float2*)(X0 + (size_t)c0 * D + lane * 2);
        float2 xa1 = *(const float2*)(X0 + (size_t)c1 * D + lane * 2);
        float2 xa2 = *(const float2*)(X0 + (size_t)c2 * D + lane * 2);
        float2 xa3 = *(const float2*)(X0 + (size_t)c3 * D + lane * 2);
        float2 xb0 = *(const float2*)(X1 + (size_t)c0 * D + lane * 2);
        float2 xb1 = *(const float2*)(X1 + (size_t)c1 * D + lane * 2);
        float2 xb2 = *(const float2*)(X1 + (size_t)c2 * D + lane * 2);
        float2 xb3 = *(const float2*)(X1 + (size_t)c3 * D + lane * 2);
        a0 = fmaf(w0, xa0.x, a0); a1 = fmaf(w0, xa0.y, a1);
        a0 = fmaf(w1, xa1.x, a0); a1 = fmaf(w1, xa1.y, a1);
        a0 = fmaf(w2, xa2.x, a0); a1 = fmaf(w2, xa2.y, a1);
        a0 = fmaf(w3, xa3.x, a0); a1 = fmaf(w3, xa3.y, a1);
        b0 = fmaf(w0, xb0.x, b0); b1 = fmaf(w0, xb0.y, b1);
        b0 = fmaf(w1, xb1.x, b0); b1 = fmaf(w1, xb1.y, b1);
        b0 = fmaf(w2, xb2.x, b0); b1 = fmaf(w2, xb2.y, b1);
        b0 = fmaf(w3, xb3.x, b0); b1 = fmaf(w3, xb3.y, b1);
    }
    for (; i < e; ++i) {
        int cc = ecol[i];
        float w = eval[i];
        float2 xa = *(const float2*)(X0 + (size_t)cc * D + lane * 2);
        float2 xb = *(const float2*)(X1 + (size_t)cc * D + lane * 2);
        a0 = fmaf(w, xa.x, a0); a1 = fmaf(w, xa.y, a1);
        b0 = fmaf(w, xb.x, b0); b1 = fmaf(w, xb.y, b1);
    }
    *(float2*)(Y0 + (size_t)row * D + lane * 2) = make_float2(a0, a1);
    *(float2*)(Y1 + (size_t)row * D + lane * 2) = make_float2(b0, b1);
}

// ---------------------------------------------------------------- BN stats (dual matrix read-only fuse, f64 partials)
__global__ __launch_bounds__(128) void k_bnstats2(const float* __restrict__ X0, const float* __restrict__ X1,
    double* __restrict__ psum, double* __restrict__ pssq)
{
    const float* __restrict__ X = blockIdx.y ? X1 : X0;
    int d = threadIdx.x;
    int r0 = blockIdx.x * 128;
    double s = 0.0, q = 0.0;
#pragma unroll 4
    for (int r = r0; r < r0 + 128; ++r) {
        double v = (double)X[(size_t)r * D + d];
        s += v; q = fma(v, v, q);
    }
    psum[blockIdx.y * 65536 + blockIdx.x * 128 + d] = s;
    pssq[blockIdx.y * 65536 + blockIdx.x * 128 + d] = q;
}

__global__ void k_bnfin(const double* __restrict__ psum, const double* __restrict__ pssq,
    const float* __restrict__ gamma, const float* __restrict__ beta,
    double* __restrict__ a, double* __restrict__ c, int nb, int layer)
{
    int t = threadIdx.x;
    if (t >= nb * 128) return;
    int blk = t >> 7, d = t & 127;
    const double* ps = psum + blk * 65536;
    const double* pq = pssq + blk * 65536;
    double s = 0.0, q = 0.0;
    for (int j = 0; j < 512; ++j) { s += ps[j * 128 + d]; q += pq[j * 128 + d]; }
    double m = s * (1.0 / 65536.0);
    double v = q * (1.0 / 65536.0) - m * m;
    double aa = (double)gamma[layer * 128 + d] / sqrt(v + 1e-5);
    a[t] = aa;
    c[t] = (double)beta[layer * 128 + d] - m * aa;
}

// ---------------------------------------------------------------- elementwise (f32, f4)
// o may alias p1 (same-index elementwise) -> no __restrict__ on p1/o.
__global__ __launch_bounds__(256) void k_hidden(const f4* __restrict__ p0, const f4* p1,
    const double* __restrict__ a, const double* __restrict__ c, f4* o)
{
    int i = blockIdx.x * 256 + threadIdx.x;
    int d4 = (i & 31) * 4;
    f4 x = p0[i], y = p1[i];
    f4 r;
#pragma unroll
    for (int j = 0; j < 4; ++j) {
        float a0 = (float)a[d4 + j], c0 = (float)c[d4 + j];
        float a1 = (float)a[128 + d4 + j], c1 = (float)c[128 + d4 + j];
        float xv = (&x.x)[j], yv = (&y.x)[j];
        (&r.x)[j] = 0.5f * (fmaxf(fmaf(xv, a0, c0), 0.f) + fmaxf(fmaf(yv, a1, c1), 0.f));
    }
    o[i] = r;
}

__global__ __launch_bounds__(256) void k_bnapply(f4* __restrict__ H,
    const double* __restrict__ a, const double* __restrict__ c)
{
    int i = blockIdx.x * 256 + threadIdx.x;
    int d4 = (i & 31) * 4;
    f4 x = H[i];
#pragma unroll
    for (int j = 0; j < 4; ++j) {
        float a0 = (float)a[d4 + j], c0 = (float)c[d4 + j];
        (&x.x)[j] = fmaxf(fmaf((&x.x)[j], a0, c0), 0.f);
    }
    H[i] = x;
}

// ---------------------------------------------------------------- concat MLP (f32, 4 elems/thread, f4 LDS weight reads)
// ROUND-11 LESSON: LDS-cached weights (133 µs) beat "uniform" global loads (162 µs) —
// the compiler does not batch per-iteration uniform f4 loads onto the s_load path.
__global__ __launch_bounds__(256) void k_concat(const f4* __restrict__ h0, const f4* __restrict__ h1,
    const f4* __restrict__ h2, const f4* __restrict__ h3,
    const float* __restrict__ w1, const float* __restrict__ b1,
    const float* __restrict__ w2, const float* __restrict__ b2,
    f4* __restrict__ Hpre)
{
    __shared__ __align__(16) float sw0[128], sw1_[128], sw2_[128], sw3[128], sv[128], sb[128];
    int t = threadIdx.x;
    if (t < 128) {
        sw0[t] = w1[t];        sw1_[t] = w1[128 + t];
        sw2_[t] = w1[256 + t]; sw3[t]  = w1[384 + t];
        sv[t]  = w2[t];        sb[t]   = b1[t];
    }
    __syncthreads();
    int i = blockIdx.x * 256 + t;  // f4 units, < N*D/4
    f4 x0 = h0[i], x1 = h1[i], x2 = h2[i], x3 = h3[i];
    float bb2 = b2[0];
    float acc0 = bb2, acc1 = bb2, acc2 = bb2, acc3 = bb2;
    for (int h4 = 0; h4 < D; h4 += 4) {
        f4 cw0 = *(const f4*)&sw0[h4];
        f4 cw1 = *(const f4*)&sw1_[h4];
        f4 cw2 = *(const f4*)&sw2_[h4];
        f4 cw3 = *(const f4*)&sw3[h4];
        f4 cbb = *(const f4*)&sb[h4];
        f4 cvv = *(const f4*)&sv[h4];
#pragma unroll
        for (int j = 0; j < 4; ++j) {
            float w0 = (&cw0.x)[j], ww1 = (&cw1.x)[j], ww2 = (&cw2.x)[j], w3 = (&cw3.x)[j];
            float bb = (&cbb.x)[j], vv = (&cvv.x)[j];
            float t0 = fmaf(x3.x, w3, fmaf(x2.x, ww2, fmaf(x1.x, ww1, fmaf(x0.x, w0, bb))));
            float t1 = fmaf(x3.y, w3, fmaf(x2.y, ww2, fmaf(x1.y, ww1, fmaf(x0.y, w0, bb))));
            float t2 = fmaf(x3.z, w3, fmaf(x2.z, ww2, fmaf(x1.z, ww1, fmaf(x0.z, w0, bb))));
            float t3 = fmaf(x3.w, w3, fmaf(x2.w, ww2, fmaf(x1.w, ww1, fmaf(x0.w, w0, bb))));
            acc0 = fmaf(fmaxf(t0, 0.f), vv, acc0);
            acc1 = fmaf(fmaxf(t1, 0.f), vv, acc1);
            acc2 = fmaf(fmaxf(t2, 0.f), vv, acc2);
            acc3 = fmaf(fmaxf(t3, 0.f), vv, acc3);
        }
    }
    f4 r; r.x = acc0; r.y = acc1; r.z = acc2; r.w = acc3;
    Hpre[i] = r;
}

// ---------------------------------------------------------------- S = softmax(hid @ w2 + b2) (f32)
__global__ __launch_bounds__(256) void k_s(const float* __restrict__ hid,
    const float* __restrict__ w2, const float* __restrict__ b2, float* __restrict__ S)
{
    int n = blockIdx.x * 256 + threadIdx.x;
    if (n >= NN) return;
    const float* hr = hid + (size_t)n * D;
    float s[10];
#pragma unroll
    for (int k = 0; k < 10; ++k) s[k] = b2[k];
    for (int h = 0; h < D; h += 4) {
        f4 hv = *(const f4*)(hr + h);
#pragma unroll
        for (int k = 0; k < 10; ++k) {
            s[k] = fmaf(hv.x, w2[(h + 0) * 10 + k], s[k]);
            s[k] = fmaf(hv.y, w2[(h + 1) * 10 + k], s[k]);
            s[k] = fmaf(hv.z, w2[(h + 2) * 10 + k], s[k]);
            s[k] = fmaf(hv.w, w2[(h + 3) * 10 + k], s[k]);
        }
    }
    float m = s[0];
#pragma unroll
    for (int k = 1; k < 10; ++k) m = fmaxf(m, s[k]);
    float e[10], sum = 0.f;
#pragma unroll
    for (int k = 0; k < 10; ++k) { e[k] = expf(s[k] - m); sum += e[k]; }
    float inv = 1.f / sum;
#pragma unroll
    for (int k = 0; k < 10; ++k) S[(size_t)n * 10 + k] = e[k] * inv;
}

// ---------------------------------------------------------------- E_all (f32 in, f64 accum, dual store)
__global__ __launch_bounds__(256) void k_eall(const float* __restrict__ S, const float* __restrict__ H,
    const int* __restrict__ off, float* __restrict__ Eo, double* __restrict__ E64)
{
    int g = blockIdx.x;
    int d = threadIdx.x & 127;
    int half = threadIdx.x >> 7;
    double acc[5] = {0.0, 0.0, 0.0, 0.0, 0.0};
    int s0 = off[g], s1 = off[g + 1];
    for (int n = s0; n < s1; ++n) {
        double hv = (double)H[(size_t)n * D + d];
#pragma unroll
        for (int j = 0; j < 5; ++j) acc[j] = fma((double)S[(size_t)n * 10 + half * 5 + j], hv, acc[j]);
    }
#pragma unroll
    for (int j = 0; j < 5; ++j) {
        size_t o = (size_t)g * 1280 + (half * 5 + j) * D + d;
        Eo[o] = (float)acc[j];
        E64[o] = acc[j];
    }
}

// ---------------------------------------------------------------- graph offsets
__global__ void k_off(const int* __restrict__ gi, int* __restrict__ off)
{
    int g = blockIdx.x * 256 + threadIdx.x;
    if (g > GG) return;
    int lo = 0, hi = NN;
    while (lo < hi) { int mid = (lo + hi) >> 1; if (gi[mid] < g) lo = mid + 1; else hi = mid; }
    off[g] = lo;
}

// ---------------------------------------------------------------- corr
__global__ void k_corr(const float* __restrict__ ci, const float* __restrict__ ca, float* __restrict__ corr)
{
    int t = threadIdx.x;
    if (t >= 160) return;
    int r = t / 16, c = t % 16;
    double m = -1e300;
    for (int i = 0; i < 10; ++i) m = fmax(m, (double)ci[i * 16 + c]);
    double s = 0.0;
    for (int i = 0; i < 10; ++i) s += exp((double)ci[i * 16 + c] - m);
    double vi = exp((double)ci[r * 16 + c] - m) / s;
    double m2 = -1e300;
    for (int j = 0; j < 16; ++j) m2 = fmax(m2, (double)ca[r * 16 + j]);
    double s2 = 0.0;
    for (int j = 0; j < 16; ++j) s2 += exp((double)ca[r * 16 + j] - m2);
    double va = exp((double)ca[r * 16 + c] - m2) / s2;
    corr[t] = (float)(vi * va);
}

// ---------------------------------------------------------------- JAX threefry gumbel — PARTITIONABLE (verified)
__device__ __forceinline__ unsigned tf_rotl(unsigned x, unsigned n) { return (x << n) | (x >> (32u - n)); }

__global__ void k_gumbel(double* __restrict__ out)
{
    int i = blockIdx.x * 256 + threadIdx.x;
    if (i >= 5120) return;
    unsigned x0 = 0u;
    unsigned x1 = (unsigned)i;
    const unsigned ks0 = 0u, ks1 = 42u;
    const unsigned ks2 = 0x1BD11BDAu ^ ks0 ^ ks1;
    x0 += ks0; x1 += ks1;
#define TF_ROUND(rr) { x0 += x1; x1 = tf_rotl(x1, rr); x1 ^= x0; }
    TF_ROUND(13) TF_ROUND(15) TF_ROUND(26) TF_ROUND(6)
    x0 += ks1; x1 += ks2 + 1u;
    TF_ROUND(17) TF_ROUND(29) TF_ROUND(16) TF_ROUND(24)
    x0 += ks2; x1 += ks0 + 2u;
    TF_ROUND(13) TF_ROUND(15) TF_ROUND(26) TF_ROUND(6)
    x0 += ks0; x1 += ks1 + 3u;
    TF_ROUND(17) TF_ROUND(29) TF_ROUND(16) TF_ROUND(24)
    x0 += ks1; x1 += ks2 + 4u;
    TF_ROUND(13) TF_ROUND(15) TF_ROUND(26) TF_ROUND(6)
    x0 += ks2; x1 += ks0 + 5u;
#undef TF_ROUND
    unsigned bits = x0 ^ x1;
    unsigned fb = (bits >> 9) | 0x3f800000u;
    float f = __uint_as_float(fb) - 1.0f;
    const float tinyf = 1.1754943508222875e-38f;
    float u32v = fmaxf(tinyf, f * (1.0f - tinyf) + tinyf);
    out[i] = -log(-log((double)u32v));
}

// ---------------------------------------------------------------- pred1 + sampling (f64)
__global__ __launch_bounds__(64) void k_pred1(const double* __restrict__ E64, const float* __restrict__ fw,
    const float* __restrict__ fb, const double* __restrict__ gum, const int* __restrict__ tgt,
    const float* __restrict__ corr, float* __restrict__ pred1, float* __restrict__ ind,
    float* __restrict__ cmask)
{
    int g = blockIdx.x;
    int l = threadIdx.x;
    double acc[10];
#pragma unroll
    for (int c = 0; c < 10; ++c) acc[c] = 0.0;
    for (int i = l; i < 1280; i += 64) {
        double e = E64[(size_t)g * 1280 + i];
#pragma unroll
        for (int c = 0; c < 10; ++c) acc[c] = fma(e, (double)fw[i * 10 + c], acc[c]);
    }
#pragma unroll
    for (int c = 0; c < 10; ++c) {
        double v = acc[c];
        for (int o = 32; o > 0; o >>= 1) v += __shfl_down(v, o, 64);
        acc[c] = v;
    }
    if (l == 0) {
        double best = -1e300; int bi = 0;
        for (int c = 0; c < 10; ++c) {
            double p = acc[c] + (double)fb[c];
            pred1[g * 10 + c] = (float)p;
            double y = p + gum[g * 10 + c];
            if (y > best) { best = y; bi = c; }
        }
        ind[g] = (bi == tgt[g]) ? 1.f : 0.f;
        for (int f = 0; f < 16; ++f) cmask[g * 16 + f] = corr[bi * 16 + f];
    }
}

// ---------------------------------------------------------------- Q + feature_mask (f32)
__global__ __launch_bounds__(128) void k_q(const float* __restrict__ Eo, const float* __restrict__ w1,
    const float* __restrict__ b1, const float* __restrict__ w2, const float* __restrict__ b2,
    const float* __restrict__ cmask, float* __restrict__ Q, float* __restrict__ fm)
{
    int gk = blockIdx.x;
    int g = gk / 10;
    int h = threadIdx.x;
    __shared__ float e[128];
    __shared__ float hh[128];
    __shared__ float qv[16];
    __shared__ float pr[16];
    e[h] = Eo[(size_t)gk * D + h];
    __syncthreads();
    float acc = b1[h];
#pragma unroll 8
    for (int d = 0; d < D; ++d) acc = fmaf(e[d], w1[d * D + h], acc);
    hh[h] = fmaxf(acc, 0.f);
    __syncthreads();
    if (h < 16) {
        float s = b2[h];
        for (int d = 0; d < D; ++d) s = fmaf(hh[d], w2[d * 16 + h], s);
        qv[h] = s;
    }
    __syncthreads();
    if (h < 16) {
        float m = qv[0];
        for (int f = 1; f < 16; ++f) m = fmaxf(m, qv[f]);
        pr[h] = expf(qv[h] - m);
    }
    __syncthreads();
    if (h < 16) {
        float s = 0.f;
        for (int f = 0; f < 16; ++f) s += pr[f];
        float q = pr[h] / s;
        Q[(size_t)gk * 16 + h] = q;
        qv[h] = q * cmask[g * 16 + h];
    }
    __syncthreads();
    if (h == 0) {
        float s = 0.f;
        for (int f = 0; f < 16; ++f) s += qv[f];
        fm[gk] = s;
    }
}

// ---------------------------------------------------------------- pred2 (f64 accum from E64)
__global__ __launch_bounds__(64) void k_pred2(const double* __restrict__ E64, const float* __restrict__ fw,
    const float* __restrict__ fb, const float* __restrict__ fm, float* __restrict__ pred2)
{
    int g = blockIdx.x;
    int l = threadIdx.x;
    double acc[10];
#pragma unroll
    for (int c = 0; c < 10; ++c) acc[c] = 0.0;
    for (int i = l; i < 1280; i += 64) {
        int k = i >> 7;
        double e = E64[(size_t)g * 1280 + i] * (double)fm[g * 10 + k];
#pragma unroll
        for (int c = 0; c < 10; ++c) acc[c] = fma(e, (double)fw[i * 10 + c], acc[c]);
    }
#pragma unroll
    for (int c = 0; c < 10; ++c) {
        double v = acc[c];
        for (int o = 32; o > 0; o >>= 1) v += __shfl_down(v, o, 64);
        acc[c] = v;
    }
    if (l == 0)
        for (int c = 0; c < 10; ++c) pred2[g * 10 + c] = (float)(acc[c] + (double)fb[c]);
}

// ================================================================ host
extern "C" void kernel_launch(void* const* d_in, const int* in_sizes, int n_in,
                              void* d_out, int out_size, void* d_ws, size_t ws_size,
                              hipStream_t stream)
{
    const float* features = (const float*)d_in[0];
    const int*   W_row    = (const int*)d_in[1];
    const int*   W_col    = (const int*)d_in[2];
    const float* W_vals   = (const float*)d_in[3];
    const int*   gi       = (const int*)d_in[4];
    const int*   targets  = (const int*)d_in[5];
    const float* enc_w1   = (const float*)d_in[6];
    const float* enc_b1   = (const float*)d_in[7];
    const float* enc_w2   = (const float*)d_in[8];
    const float* enc_b2   = (const float*)d_in[9];
    const float* bn_gamma = (const float*)d_in[10];
    const float* bn_beta  = (const float*)d_in[11];
    const float* concat_w1= (const float*)d_in[12];
    const float* concat_b1= (const float*)d_in[13];
    const float* concat_w2= (const float*)d_in[14];
    const float* concat_b2= (const float*)d_in[15];
    const float* smlp_w1  = (const float*)d_in[16];
    const float* smlp_b1  = (const float*)d_in[17];
    const float* smlp_w2  = (const float*)d_in[18];
    const float* smlp_b2  = (const float*)d_in[19];
    const float* proto_w1 = (const float*)d_in[20];
    const float* proto_b1 = (const float*)d_in[21];
    const float* proto_w2 = (const float*)d_in[22];
    const float* proto_b2 = (const float*)d_in[23];
    const float* final_w  = (const float*)d_in[24];
    const float* final_b  = (const float*)d_in[25];
    const float* corr_i   = (const float*)d_in[26];
    const float* corr_a   = (const float*)d_in[27];

    float* out = (float*)d_out;
    float* o_pred1 = out + 0;
    float* o_pred2 = out + 5120;
    float* o_S     = out + 10240;
    float* o_H     = out + 665600;
    float* o_ind   = out + 9054208;
    float* o_E     = out + 9054720;
    float* o_Q     = out + 9710080;

    // ---------------- workspace arena (total ~240 MiB — proven fit; do NOT grow: round-8 crash)
    char* base = (char*)d_ws;
    size_t off = 0;
    auto alloc = [&](size_t n) -> char* {
        char* r = base + off;
        off = (off + n + 255) & ~(size_t)255;
        return r;
    };
    int*    d_off   = (int*)alloc(513 * 4);
    double* d_a     = (double*)alloc(256 * 8);
    double* d_c     = (double*)alloc(256 * 8);
    double* d_gum   = (double*)alloc(5120 * 8);
    float*  d_corr  = (float*)alloc(160 * 4);
    float*  d_cmask = (float*)alloc(512 * 16 * 4);
    float*  d_fm    = (float*)alloc(5120 * 4);
    double* psum    = (double*)alloc(2 * 512 * 128 * 8);
    double* pssq    = (double*)alloc(2 * 512 * 128 * 8);
    int*    cnt     = (int*)alloc((size_t)NN * 4);
    int*    excl    = (int*)alloc((size_t)NN * 4);
    int*    bsum    = (int*)alloc(256 * 4);
    int*    boff    = (int*)alloc(256 * 4);
    int*    rowptr  = (int*)alloc((size_t)(NN + 1) * 4);
    int*    cursor  = (int*)alloc((size_t)NN * 4);
    int*    ecol    = (int*)alloc((size_t)EE * 4);
    float*  evalv   = (float*)alloc((size_t)EE * 4);
    double* E64     = (double*)alloc((size_t)GG * 1280 * 8);

    const size_t SZ = (size_t)NN * D * 4;   // 32 MiB per f32 tensor
    float* rot0 = (float*)alloc(SZ);
    float* rot1 = (float*)alloc(SZ);
    float* rot2 = (float*)alloc(SZ);
    float* h0   = (float*)alloc(SZ);
    float* h1   = (float*)alloc(SZ);
    float* h2   = (float*)alloc(SZ);
    float* h3   = (float*)alloc(SZ);
    float* Tenc = h2;        // N x 256 f32 spans h2+h3 (dead after encoder)
    float* hid2 = rot0;      // smlp hidden reuses rot region after prop loop

    // ---------------- small precomputations
    k_off   <<<3, 256, 0, stream>>>(gi, d_off);
    k_corr  <<<1, 256, 0, stream>>>(corr_i, corr_a, d_corr);
    k_gumbel<<<20, 256, 0, stream>>>(d_gum);

    // ---------------- CSR build
    hipMemsetAsync(cnt, 0, (size_t)NN * 4, stream);
    k_hist   <<<EE / 256, 256, 0, stream>>>(W_row, cnt);
    k_scan1  <<<256, 256, 0, stream>>>(cnt, excl, bsum);
    k_scan2  <<<1, 256, 0, stream>>>(bsum, boff);
    k_scan3  <<<256, 256, 0, stream>>>(excl, boff, rowptr, cursor);
    k_scatter<<<EE / 256, 256, 0, stream>>>(W_row, W_col, W_vals, cursor, ecol, evalv);

    // ---------------- encoder (f32); 4th GEMM fuses hidden_rep[0] = 0.5*(rot0+rot1) -> h0
    k_gemm<<<dim3(2, 512), 256, 0, stream>>>(features, enc_w1,             enc_b1,       Tenc, nullptr, nullptr, NN, 256, 128, 1);
    k_gemm<<<dim3(1, 512), 256, 0, stream>>>(Tenc,     enc_w2,             enc_b2,       rot0, nullptr, nullptr, NN, 128, 256, 0);
    k_gemm<<<dim3(2, 512), 256, 0, stream>>>(features, enc_w1 + 128 * 256, enc_b1 + 256, Tenc, nullptr, nullptr, NN, 256, 128, 1);
    k_gemm<<<dim3(1, 512), 256, 0, stream>>>(Tenc,     enc_w2 + 256 * 128, enc_b2 + 128, rot1, rot0, h0,         NN, 128, 256, 0);

    // ---------------- propagation loop: per-wave dual SpMM, zero extra memory.
    // p=0: (rot0,rot1)->(rot2,h2), hidden->h1
    // p=1: (rot2,h2)->(rot0,rot1), hidden->h2   (h2 read by spmm BEFORE hidden overwrites it)
    // p=2: (rot0,rot1)->(rot2,h3), hidden(rot2,h3)->h3 (in-place elementwise, same-index, safe)
    {
        float* hbuf[4] = { h0, h1, h2, h3 };
        float* curA = rot0; float* curB = rot1;
        float* nxtA[3] = { rot2, rot0, rot2 };
        float* nxtB[3] = { h2,   rot1, h3   };
        for (int p = 0; p < 3; ++p) {
            float* nA = nxtA[p];
            float* nB = nxtB[p];
            k_spmm_dual<<<NN / 4, 256, 0, stream>>>(rowptr, ecol, evalv, curA, nA, curB, nB);
            k_bnstats2<<<dim3(512, 2), 128, 0, stream>>>(nA, nB, psum, pssq);
            k_bnfin<<<1, 256, 0, stream>>>(psum, pssq, bn_gamma, bn_beta, d_a, d_c, 2, p);
            k_hidden<<<8192, 256, 0, stream>>>((const f4*)nA, (const f4*)nB, d_a, d_c, (f4*)hbuf[1 + p]);
            curA = nA; curB = nB;
        }
    }

    // ---------------- concat MLP -> o_H, BN+relu in place
    k_concat<<<8192, 256, 0, stream>>>((const f4*)h0, (const f4*)h1, (const f4*)h2, (const f4*)h3,
                                       concat_w1, concat_b1, concat_w2, concat_b2, (f4*)o_H);
    k_bnstats2<<<dim3(512, 1), 128, 0, stream>>>(o_H, o_H, psum, pssq);
    k_bnfin<<<1, 256, 0, stream>>>(psum, pssq, bn_gamma, bn_beta, d_a, d_c, 1, 3);
    k_bnapply<<<8192, 256, 0, stream>>>((f4*)o_H, d_a, d_c);

    // ---------------- S_all
    k_gemm<<<dim3(1, 512), 256, 0, stream>>>(o_H, smlp_w1, smlp_b1, hid2, nullptr, nullptr, NN, 128, 128, 1);
    k_s<<<256, 256, 0, stream>>>(hid2, smlp_w2, smlp_b2, o_S);

    // ---------------- E_all, heads
    k_eall <<<512, 256, 0, stream>>>(o_S, o_H, d_off, o_E, E64);
    k_pred1<<<512, 64, 0, stream>>>(E64, final_w, final_b, d_gum, targets, d_corr,
                                    o_pred1, o_ind, d_cmask);
    k_q    <<<5120, 128, 0, stream>>>(o_E, proto_w1, proto_b1, proto_w2, proto_b2,
                                      d_cmask, o_Q, d_fm);
    k_pred2<<<512, 64, 0, stream>>>(E64, final_w, final_b, d_fm, o_pred2);

    (void)in_sizes; (void)n_in; (void)out_size; (void)ws_size;
}

// Round 13
// 1312.162 us; speedup vs baseline: 1.0076x; 1.0068x over previous
//
#include <hip/hip_runtime.h>
#include <math.h>

#define NN 65536
#define EE 1048576
#define GG 512
#define D  128

typedef float4 f4;

// ---------------------------------------------------------------- GEMM (fp32, 128x128 tile, 8x8 micro, split 4+4,
//   double-buffered LDS, single barrier per K-step, optional fused mean epilogue)
__global__ __launch_bounds__(256) void k_gemm(const float* __restrict__ A,
    const float* __restrict__ B, const float* __restrict__ bias,
    float* __restrict__ C, const float* __restrict__ mix_src, float* __restrict__ mix_dst,
    int M, int N, int K, int relu)
{
    __shared__ __align__(16) float As[2][16][132];
    __shared__ __align__(16) float Bs[2][16][132];
    int tid = threadIdx.x;
    int tx = tid & 15, ty = tid >> 4;
    int row0 = blockIdx.y * 128, col0 = blockIdx.x * 128;
    float acc[8][8];
#pragma unroll
    for (int i = 0; i < 8; ++i)
#pragma unroll
        for (int j = 0; j < 8; ++j) acc[i][j] = 0.f;
    int ar = tid >> 1, ac = (tid & 1) * 8;
    int br = tid >> 4, bc = (tid & 15) * 8;
    const float* aptr = A + (size_t)(row0 + ar) * K + ac;
    const float* bptr = B + (size_t)br * N + col0 + bc;

    f4 pa0 = *(const f4*)(aptr);
    f4 pa1 = *(const f4*)(aptr + 4);
    f4 pb0 = *(const f4*)(bptr);
    f4 pb1 = *(const f4*)(bptr + 4);
    As[0][ac + 0][ar] = pa0.x; As[0][ac + 1][ar] = pa0.y; As[0][ac + 2][ar] = pa0.z; As[0][ac + 3][ar] = pa0.w;
    As[0][ac + 4][ar] = pa1.x; As[0][ac + 5][ar] = pa1.y; As[0][ac + 6][ar] = pa1.z; As[0][ac + 7][ar] = pa1.w;
    *(f4*)&Bs[0][br][bc] = pb0; *(f4*)&Bs[0][br][bc + 4] = pb1;
    __syncthreads();

    int cur = 0;
    for (int k0 = 0; k0 < K; k0 += 16) {
        int last = (k0 + 16 >= K);
        if (!last) {
            pa0 = *(const f4*)(aptr + k0 + 16);
            pa1 = *(const f4*)(aptr + k0 + 16 + 4);
            pb0 = *(const f4*)(bptr + (size_t)(k0 + 16) * N);
            pb1 = *(const f4*)(bptr + (size_t)(k0 + 16) * N + 4);
        }
        const float (*Ac)[132] = As[cur];
        const float (*Bc)[132] = Bs[cur];
#pragma unroll
        for (int kk = 0; kk < 16; ++kk) {
            float a[8], b[8];
            *(f4*)&a[0] = *(const f4*)&Ac[kk][ty * 4];
            *(f4*)&a[4] = *(const f4*)&Ac[kk][64 + ty * 4];
            *(f4*)&b[0] = *(const f4*)&Bc[kk][tx * 4];
            *(f4*)&b[4] = *(const f4*)&Bc[kk][64 + tx * 4];
#pragma unroll
            for (int i = 0; i < 8; ++i)
#pragma unroll
                for (int j = 0; j < 8; ++j) acc[i][j] = fmaf(a[i], b[j], acc[i][j]);
        }
        if (!last) {
            int nxt = cur ^ 1;
            As[nxt][ac + 0][ar] = pa0.x; As[nxt][ac + 1][ar] = pa0.y; As[nxt][ac + 2][ar] = pa0.z; As[nxt][ac + 3][ar] = pa0.w;
            As[nxt][ac + 4][ar] = pa1.x; As[nxt][ac + 5][ar] = pa1.y; As[nxt][ac + 6][ar] = pa1.z; As[nxt][ac + 7][ar] = pa1.w;
            *(f4*)&Bs[nxt][br][bc] = pb0; *(f4*)&Bs[nxt][br][bc + 4] = pb1;
            __syncthreads();
            cur = nxt;
        }
    }

    f4 bia0 = *(const f4*)(bias + col0 + tx * 4);
    f4 bia1 = *(const f4*)(bias + col0 + 64 + tx * 4);
#pragma unroll
    for (int i = 0; i < 8; ++i) {
        int r = row0 + ((i < 4) ? (ty * 4 + i) : (64 + ty * 4 + i - 4));
        f4 v0, v1;
#pragma unroll
        for (int j = 0; j < 4; ++j) {
            float u0 = acc[i][j] + (&bia0.x)[j];
            float u1 = acc[i][j + 4] + (&bia1.x)[j];
            if (relu) { u0 = fmaxf(u0, 0.f); u1 = fmaxf(u1, 0.f); }
            (&v0.x)[j] = u0; (&v1.x)[j] = u1;
        }
        *(f4*)(C + (size_t)r * N + col0 + tx * 4) = v0;
        *(f4*)(C + (size_t)r * N + col0 + 64 + tx * 4) = v1;
        if (mix_dst) {
            f4 m0 = *(const f4*)(mix_src + (size_t)r * N + col0 + tx * 4);
            f4 m1 = *(const f4*)(mix_src + (size_t)r * N + col0 + 64 + tx * 4);
            f4 w0, w1;
#pragma unroll
            for (int j = 0; j < 4; ++j) {
                (&w0.x)[j] = 0.5f * ((&v0.x)[j] + (&m0.x)[j]);
                (&w1.x)[j] = 0.5f * ((&v1.x)[j] + (&m1.x)[j]);
            }
            *(f4*)(mix_dst + (size_t)r * N + col0 + tx * 4) = w0;
            *(f4*)(mix_dst + (size_t)r * N + col0 + 64 + tx * 4) = w1;
        }
    }
}

// ---------------------------------------------------------------- CSR build
__global__ __launch_bounds__(256) void k_hist(const int* __restrict__ Wr, int* __restrict__ cnt)
{
    int e = blockIdx.x * 256 + threadIdx.x;
    if (e < EE) atomicAdd(&cnt[Wr[e]], 1);
}

__global__ __launch_bounds__(256) void k_scan1(const int* __restrict__ cnt,
    int* __restrict__ excl, int* __restrict__ bsum)
{
    __shared__ int s[256];
    int b = blockIdx.x, t = threadIdx.x;
    int v = cnt[b * 256 + t];
    s[t] = v; __syncthreads();
    for (int o = 1; o < 256; o <<= 1) {
        int x = (t >= o) ? s[t - o] : 0;
        __syncthreads();
        s[t] += x;
        __syncthreads();
    }
    excl[b * 256 + t] = s[t] - v;
    if (t == 255) bsum[b] = s[255];
}

__global__ void k_scan2(const int* __restrict__ bsum, int* __restrict__ boff)
{
    __shared__ int s[256];
    int t = threadIdx.x;
    int v = bsum[t]; s[t] = v; __syncthreads();
    for (int o = 1; o < 256; o <<= 1) {
        int x = (t >= o) ? s[t - o] : 0;
        __syncthreads();
        s[t] += x;
        __syncthreads();
    }
    boff[t] = s[t] - v;
}

__global__ __launch_bounds__(256) void k_scan3(const int* __restrict__ excl, const int* __restrict__ boff,
    int* __restrict__ rowptr, int* __restrict__ cursor)
{
    int i = blockIdx.x * 256 + threadIdx.x;
    int v = excl[i] + boff[i >> 8];
    rowptr[i] = v; cursor[i] = v;
    if (i == 0) rowptr[NN] = EE;
}

__global__ __launch_bounds__(256) void k_scatter(const int* __restrict__ Wr, const int* __restrict__ Wc,
    const float* __restrict__ Wv, int* __restrict__ cursor, int* __restrict__ ecol, float* __restrict__ ev)
{
    int e = blockIdx.x * 256 + threadIdx.x;
    if (e >= EE) return;
    int r = Wr[e];
    int p = atomicAdd(&cursor[r], 1);
    ecol[p] = Wc[e]; ev[p] = Wv[e];
}

// ---------------------------------------------------------------- SpMM (CSR, wave/row, 4-edge chunks, dual matrix via blockIdx.y)
// ROUND-12 LESSON: blockIdx.y split (each wave streams ONE matrix) beats per-wave dual
// (143.6 vs 148.3 µs, FETCH 482 vs 503 MB) — better per-CU L2 locality.
// SAFETY (G16): Y0,Y1 disjoint from BOTH X0,X1.
__global__ __launch_bounds__(256) void k_spmm2(const int* __restrict__ rowptr,
    const int* __restrict__ ecol, const float* __restrict__ eval,
    const float* __restrict__ X0, float* __restrict__ Y0,
    const float* __restrict__ X1, float* __restrict__ Y1)
{
    int row = blockIdx.x * 4 + (threadIdx.x >> 6);
    int lane = threadIdx.x & 63;
    const float* __restrict__ X = blockIdx.y ? X1 : X0;
    float* __restrict__ Y = blockIdx.y ? Y1 : Y0;
    int s = rowptr[row], e = rowptr[row + 1];
    float a0 = 0.f, a1 = 0.f;
    int i = s;
    for (; i + 4 <= e; i += 4) {
        int   c0 = ecol[i], c1 = ecol[i + 1], c2 = ecol[i + 2], c3 = ecol[i + 3];
        float w0 = eval[i], w1 = eval[i + 1], w2 = eval[i + 2], w3 = eval[i + 3];
        float2 x0 = *(const float2*)(X + (size_t)c0 * D + lane * 2);
        float2 x1 = *(const float2*)(X + (size_t)c1 * D + lane * 2);
        float2 x2 = *(const float2*)(X + (size_t)c2 * D + lane * 2);
        float2 x3 = *(const float2*)(X + (size_t)c3 * D + lane * 2);
        a0 = fmaf(w0, x0.x, a0); a1 = fmaf(w0, x0.y, a1);
        a0 = fmaf(w1, x1.x, a0); a1 = fmaf(w1, x1.y, a1);
        a0 = fmaf(w2, x2.x, a0); a1 = fmaf(w2, x2.y, a1);
        a0 = fmaf(w3, x3.x, a0); a1 = fmaf(w3, x3.y, a1);
    }
    for (; i < e; ++i) {
        int cc = ecol[i];
        float w = eval[i];
        float2 x = *(const float2*)(X + (size_t)cc * D + lane * 2);
        a0 = fmaf(w, x.x, a0);
        a1 = fmaf(w, x.y, a1);
    }
    *(float2*)(Y + (size_t)row * D + lane * 2) = make_float2(a0, a1);
}

// ---------------------------------------------------------------- BN stats (dual matrix read-only fuse, f64 partials)
__global__ __launch_bounds__(128) void k_bnstats2(const float* __restrict__ X0, const float* __restrict__ X1,
    double* __restrict__ psum, double* __restrict__ pssq)
{
    const float* __restrict__ X = blockIdx.y ? X1 : X0;
    int d = threadIdx.x;
    int r0 = blockIdx.x * 128;
    double s = 0.0, q = 0.0;
#pragma unroll 4
    for (int r = r0; r < r0 + 128; ++r) {
        double v = (double)X[(size_t)r * D + d];
        s += v; q = fma(v, v, q);
    }
    psum[blockIdx.y * 65536 + blockIdx.x * 128 + d] = s;
    pssq[blockIdx.y * 65536 + blockIdx.x * 128 + d] = q;
}

__global__ void k_bnfin(const double* __restrict__ psum, const double* __restrict__ pssq,
    const float* __restrict__ gamma, const float* __restrict__ beta,
    double* __restrict__ a, double* __restrict__ c, int nb, int layer)
{
    int t = threadIdx.x;
    if (t >= nb * 128) return;
    int blk = t >> 7, d = t & 127;
    const double* ps = psum + blk * 65536;
    const double* pq = pssq + blk * 65536;
    double s = 0.0, q = 0.0;
    for (int j = 0; j < 512; ++j) { s += ps[j * 128 + d]; q += pq[j * 128 + d]; }
    double m = s * (1.0 / 65536.0);
    double v = q * (1.0 / 65536.0) - m * m;
    double aa = (double)gamma[layer * 128 + d] / sqrt(v + 1e-5);
    a[t] = aa;
    c[t] = (double)beta[layer * 128 + d] - m * aa;
}

// ---------------------------------------------------------------- elementwise (f32, f4)
// o may alias p1 (same-index elementwise) -> no __restrict__ on p1/o.
__global__ __launch_bounds__(256) void k_hidden(const f4* __restrict__ p0, const f4* p1,
    const double* __restrict__ a, const double* __restrict__ c, f4* o)
{
    int i = blockIdx.x * 256 + threadIdx.x;
    int d4 = (i & 31) * 4;
    f4 x = p0[i], y = p1[i];
    f4 r;
#pragma unroll
    for (int j = 0; j < 4; ++j) {
        float a0 = (float)a[d4 + j], c0 = (float)c[d4 + j];
        float a1 = (float)a[128 + d4 + j], c1 = (float)c[128 + d4 + j];
        float xv = (&x.x)[j], yv = (&y.x)[j];
        (&r.x)[j] = 0.5f * (fmaxf(fmaf(xv, a0, c0), 0.f) + fmaxf(fmaf(yv, a1, c1), 0.f));
    }
    o[i] = r;
}

__global__ __launch_bounds__(256) void k_bnapply(f4* __restrict__ H,
    const double* __restrict__ a, const double* __restrict__ c)
{
    int i = blockIdx.x * 256 + threadIdx.x;
    int d4 = (i & 31) * 4;
    f4 x = H[i];
#pragma unroll
    for (int j = 0; j < 4; ++j) {
        float a0 = (float)a[d4 + j], c0 = (float)c[d4 + j];
        (&x.x)[j] = fmaxf(fmaf((&x.x)[j], a0, c0), 0.f);
    }
    H[i] = x;
}

// ---------------------------------------------------------------- concat MLP (f32, 4 elems/thread, f4 LDS weight reads)
// ROUND-11 LESSON: LDS-cached weights (133 µs) beat "uniform" global loads (162 µs).
__global__ __launch_bounds__(256) void k_concat(const f4* __restrict__ h0, const f4* __restrict__ h1,
    const f4* __restrict__ h2, const f4* __restrict__ h3,
    const float* __restrict__ w1, const float* __restrict__ b1,
    const float* __restrict__ w2, const float* __restrict__ b2,
    f4* __restrict__ Hpre)
{
    __shared__ __align__(16) float sw0[128], sw1_[128], sw2_[128], sw3[128], sv[128], sb[128];
    int t = threadIdx.x;
    if (t < 128) {
        sw0[t] = w1[t];        sw1_[t] = w1[128 + t];
        sw2_[t] = w1[256 + t]; sw3[t]  = w1[384 + t];
        sv[t]  = w2[t];        sb[t]   = b1[t];
    }
    __syncthreads();
    int i = blockIdx.x * 256 + t;  // f4 units, < N*D/4
    f4 x0 = h0[i], x1 = h1[i], x2 = h2[i], x3 = h3[i];
    float bb2 = b2[0];
    float acc0 = bb2, acc1 = bb2, acc2 = bb2, acc3 = bb2;
    for (int h4 = 0; h4 < D; h4 += 4) {
        f4 cw0 = *(const f4*)&sw0[h4];
        f4 cw1 = *(const f4*)&sw1_[h4];
        f4 cw2 = *(const f4*)&sw2_[h4];
        f4 cw3 = *(const f4*)&sw3[h4];
        f4 cbb = *(const f4*)&sb[h4];
        f4 cvv = *(const f4*)&sv[h4];
#pragma unroll
        for (int j = 0; j < 4; ++j) {
            float w0 = (&cw0.x)[j], ww1 = (&cw1.x)[j], ww2 = (&cw2.x)[j], w3 = (&cw3.x)[j];
            float bb = (&cbb.x)[j], vv = (&cvv.x)[j];
            float t0 = fmaf(x3.x, w3, fmaf(x2.x, ww2, fmaf(x1.x, ww1, fmaf(x0.x, w0, bb))));
            float t1 = fmaf(x3.y, w3, fmaf(x2.y, ww2, fmaf(x1.y, ww1, fmaf(x0.y, w0, bb))));
            float t2 = fmaf(x3.z, w3, fmaf(x2.z, ww2, fmaf(x1.z, ww1, fmaf(x0.z, w0, bb))));
            float t3 = fmaf(x3.w, w3, fmaf(x2.w, ww2, fmaf(x1.w, ww1, fmaf(x0.w, w0, bb))));
            acc0 = fmaf(fmaxf(t0, 0.f), vv, acc0);
            acc1 = fmaf(fmaxf(t1, 0.f), vv, acc1);
            acc2 = fmaf(fmaxf(t2, 0.f), vv, acc2);
            acc3 = fmaf(fmaxf(t3, 0.f), vv, acc3);
        }
    }
    f4 r; r.x = acc0; r.y = acc1; r.z = acc2; r.w = acc3;
    Hpre[i] = r;
}

// ---------------------------------------------------------------- S = softmax(hid @ w2 + b2) (f32)
__global__ __launch_bounds__(256) void k_s(const float* __restrict__ hid,
    const float* __restrict__ w2, const float* __restrict__ b2, float* __restrict__ S)
{
    int n = blockIdx.x * 256 + threadIdx.x;
    if (n >= NN) return;
    const float* hr = hid + (size_t)n * D;
    float s[10];
#pragma unroll
    for (int k = 0; k < 10; ++k) s[k] = b2[k];
    for (int h = 0; h < D; h += 4) {
        f4 hv = *(const f4*)(hr + h);
#pragma unroll
        for (int k = 0; k < 10; ++k) {
            s[k] = fmaf(hv.x, w2[(h + 0) * 10 + k], s[k]);
            s[k] = fmaf(hv.y, w2[(h + 1) * 10 + k], s[k]);
            s[k] = fmaf(hv.z, w2[(h + 2) * 10 + k], s[k]);
            s[k] = fmaf(hv.w, w2[(h + 3) * 10 + k], s[k]);
        }
    }
    float m = s[0];
#pragma unroll
    for (int k = 1; k < 10; ++k) m = fmaxf(m, s[k]);
    float e[10], sum = 0.f;
#pragma unroll
    for (int k = 0; k < 10; ++k) { e[k] = expf(s[k] - m); sum += e[k]; }
    float inv = 1.f / sum;
#pragma unroll
    for (int k = 0; k < 10; ++k) S[(size_t)n * 10 + k] = e[k] * inv;
}

// ---------------------------------------------------------------- E_all (f32 in, f64 accum, dual store)
__global__ __launch_bounds__(256) void k_eall(const float* __restrict__ S, const float* __restrict__ H,
    const int* __restrict__ off, float* __restrict__ Eo, double* __restrict__ E64)
{
    int g = blockIdx.x;
    int d = threadIdx.x & 127;
    int half = threadIdx.x >> 7;
    double acc[5] = {0.0, 0.0, 0.0, 0.0, 0.0};
    int s0 = off[g], s1 = off[g + 1];
    for (int n = s0; n < s1; ++n) {
        double hv = (double)H[(size_t)n * D + d];
#pragma unroll
        for (int j = 0; j < 5; ++j) acc[j] = fma((double)S[(size_t)n * 10 + half * 5 + j], hv, acc[j]);
    }
#pragma unroll
    for (int j = 0; j < 5; ++j) {
        size_t o = (size_t)g * 1280 + (half * 5 + j) * D + d;
        Eo[o] = (float)acc[j];
        E64[o] = acc[j];
    }
}

// ---------------------------------------------------------------- graph offsets
__global__ void k_off(const int* __restrict__ gi, int* __restrict__ off)
{
    int g = blockIdx.x * 256 + threadIdx.x;
    if (g > GG) return;
    int lo = 0, hi = NN;
    while (lo < hi) { int mid = (lo + hi) >> 1; if (gi[mid] < g) lo = mid + 1; else hi = mid; }
    off[g] = lo;
}

// ---------------------------------------------------------------- corr
__global__ void k_corr(const float* __restrict__ ci, const float* __restrict__ ca, float* __restrict__ corr)
{
    int t = threadIdx.x;
    if (t >= 160) return;
    int r = t / 16, c = t % 16;
    double m = -1e300;
    for (int i = 0; i < 10; ++i) m = fmax(m, (double)ci[i * 16 + c]);
    double s = 0.0;
    for (int i = 0; i < 10; ++i) s += exp((double)ci[i * 16 + c] - m);
    double vi = exp((double)ci[r * 16 + c] - m) / s;
    double m2 = -1e300;
    for (int j = 0; j < 16; ++j) m2 = fmax(m2, (double)ca[r * 16 + j]);
    double s2 = 0.0;
    for (int j = 0; j < 16; ++j) s2 += exp((double)ca[r * 16 + j] - m2);
    double va = exp((double)ca[r * 16 + c] - m2) / s2;
    corr[t] = (float)(vi * va);
}

// ---------------------------------------------------------------- JAX threefry gumbel — PARTITIONABLE (verified)
__device__ __forceinline__ unsigned tf_rotl(unsigned x, unsigned n) { return (x << n) | (x >> (32u - n)); }

__global__ void k_gumbel(double* __restrict__ out)
{
    int i = blockIdx.x * 256 + threadIdx.x;
    if (i >= 5120) return;
    unsigned x0 = 0u;
    unsigned x1 = (unsigned)i;
    const unsigned ks0 = 0u, ks1 = 42u;
    const unsigned ks2 = 0x1BD11BDAu ^ ks0 ^ ks1;
    x0 += ks0; x1 += ks1;
#define TF_ROUND(rr) { x0 += x1; x1 = tf_rotl(x1, rr); x1 ^= x0; }
    TF_ROUND(13) TF_ROUND(15) TF_ROUND(26) TF_ROUND(6)
    x0 += ks1; x1 += ks2 + 1u;
    TF_ROUND(17) TF_ROUND(29) TF_ROUND(16) TF_ROUND(24)
    x0 += ks2; x1 += ks0 + 2u;
    TF_ROUND(13) TF_ROUND(15) TF_ROUND(26) TF_ROUND(6)
    x0 += ks0; x1 += ks1 + 3u;
    TF_ROUND(17) TF_ROUND(29) TF_ROUND(16) TF_ROUND(24)
    x0 += ks1; x1 += ks2 + 4u;
    TF_ROUND(13) TF_ROUND(15) TF_ROUND(26) TF_ROUND(6)
    x0 += ks2; x1 += ks0 + 5u;
#undef TF_ROUND
    unsigned bits = x0 ^ x1;
    unsigned fb = (bits >> 9) | 0x3f800000u;
    float f = __uint_as_float(fb) - 1.0f;
    const float tinyf = 1.1754943508222875e-38f;
    float u32v = fmaxf(tinyf, f * (1.0f - tinyf) + tinyf);
    out[i] = -log(-log((double)u32v));
}

// ---------------------------------------------------------------- pred1 + sampling (f64)
__global__ __launch_bounds__(64) void k_pred1(const double* __restrict__ E64, const float* __restrict__ fw,
    const float* __restrict__ fb, const double* __restrict__ gum, const int* __restrict__ tgt,
    const float* __restrict__ corr, float* __restrict__ pred1, float* __restrict__ ind,
    float* __restrict__ cmask)
{
    int g = blockIdx.x;
    int l = threadIdx.x;
    double acc[10];
#pragma unroll
    for (int c = 0; c < 10; ++c) acc[c] = 0.0;
    for (int i = l; i < 1280; i += 64) {
        double e = E64[(size_t)g * 1280 + i];
#pragma unroll
        for (int c = 0; c < 10; ++c) acc[c] = fma(e, (double)fw[i * 10 + c], acc[c]);
    }
#pragma unroll
    for (int c = 0; c < 10; ++c) {
        double v = acc[c];
        for (int o = 32; o > 0; o >>= 1) v += __shfl_down(v, o, 64);
        acc[c] = v;
    }
    if (l == 0) {
        double best = -1e300; int bi = 0;
        for (int c = 0; c < 10; ++c) {
            double p = acc[c] + (double)fb[c];
            pred1[g * 10 + c] = (float)p;
            double y = p + gum[g * 10 + c];
            if (y > best) { best = y; bi = c; }
        }
        ind[g] = (bi == tgt[g]) ? 1.f : 0.f;
        for (int f = 0; f < 16; ++f) cmask[g * 16 + f] = corr[bi * 16 + f];
    }
}

// ---------------------------------------------------------------- Q + feature_mask (f32)
__global__ __launch_bounds__(128) void k_q(const float* __restrict__ Eo, const float* __restrict__ w1,
    const float* __restrict__ b1, const float* __restrict__ w2, const float* __restrict__ b2,
    const float* __restrict__ cmask, float* __restrict__ Q, float* __restrict__ fm)
{
    int gk = blockIdx.x;
    int g = gk / 10;
    int h = threadIdx.x;
    __shared__ float e[128];
    __shared__ float hh[128];
    __shared__ float qv[16];
    __shared__ float pr[16];
    e[h] = Eo[(size_t)gk * D + h];
    __syncthreads();
    float acc = b1[h];
#pragma unroll 8
    for (int d = 0; d < D; ++d) acc = fmaf(e[d], w1[d * D + h], acc);
    hh[h] = fmaxf(acc, 0.f);
    __syncthreads();
    if (h < 16) {
        float s = b2[h];
        for (int d = 0; d < D; ++d) s = fmaf(hh[d], w2[d * 16 + h], s);
        qv[h] = s;
    }
    __syncthreads();
    if (h < 16) {
        float m = qv[0];
        for (int f = 1; f < 16; ++f) m = fmaxf(m, qv[f]);
        pr[h] = expf(qv[h] - m);
    }
    __syncthreads();
    if (h < 16) {
        float s = 0.f;
        for (int f = 0; f < 16; ++f) s += pr[f];
        float q = pr[h] / s;
        Q[(size_t)gk * 16 + h] = q;
        qv[h] = q * cmask[g * 16 + h];
    }
    __syncthreads();
    if (h == 0) {
        float s = 0.f;
        for (int f = 0; f < 16; ++f) s += qv[f];
        fm[gk] = s;
    }
}

// ---------------------------------------------------------------- pred2 (f64 accum from E64)
__global__ __launch_bounds__(64) void k_pred2(const double* __restrict__ E64, const float* __restrict__ fw,
    const float* __restrict__ fb, const float* __restrict__ fm, float* __restrict__ pred2)
{
    int g = blockIdx.x;
    int l = threadIdx.x;
    double acc[10];
#pragma unroll
    for (int c = 0; c < 10; ++c) acc[c] = 0.0;
    for (int i = l; i < 1280; i += 64) {
        int k = i >> 7;
        double e = E64[(size_t)g * 1280 + i] * (double)fm[g * 10 + k];
#pragma unroll
        for (int c = 0; c < 10; ++c) acc[c] = fma(e, (double)fw[i * 10 + c], acc[c]);
    }
#pragma unroll
    for (int c = 0; c < 10; ++c) {
        double v = acc[c];
        for (int o = 32; o > 0; o >>= 1) v += __shfl_down(v, o, 64);
        acc[c] = v;
    }
    if (l == 0)
        for (int c = 0; c < 10; ++c) pred2[g * 10 + c] = (float)(acc[c] + (double)fb[c]);
}

// ================================================================ host
extern "C" void kernel_launch(void* const* d_in, const int* in_sizes, int n_in,
                              void* d_out, int out_size, void* d_ws, size_t ws_size,
                              hipStream_t stream)
{
    const float* features = (const float*)d_in[0];
    const int*   W_row    = (const int*)d_in[1];
    const int*   W_col    = (const int*)d_in[2];
    const float* W_vals   = (const float*)d_in[3];
    const int*   gi       = (const int*)d_in[4];
    const int*   targets  = (const int*)d_in[5];
    const float* enc_w1   = (const float*)d_in[6];
    const float* enc_b1   = (const float*)d_in[7];
    const float* enc_w2   = (const float*)d_in[8];
    const float* enc_b2   = (const float*)d_in[9];
    const float* bn_gamma = (const float*)d_in[10];
    const float* bn_beta  = (const float*)d_in[11];
    const float* concat_w1= (const float*)d_in[12];
    const float* concat_b1= (const float*)d_in[13];
    const float* concat_w2= (const float*)d_in[14];
    const float* concat_b2= (const float*)d_in[15];
    const float* smlp_w1  = (const float*)d_in[16];
    const float* smlp_b1  = (const float*)d_in[17];
    const float* smlp_w2  = (const float*)d_in[18];
    const float* smlp_b2  = (const float*)d_in[19];
    const float* proto_w1 = (const float*)d_in[20];
    const float* proto_b1 = (const float*)d_in[21];
    const float* proto_w2 = (const float*)d_in[22];
    const float* proto_b2 = (const float*)d_in[23];
    const float* final_w  = (const float*)d_in[24];
    const float* final_b  = (const float*)d_in[25];
    const float* corr_i   = (const float*)d_in[26];
    const float* corr_a   = (const float*)d_in[27];

    float* out = (float*)d_out;
    float* o_pred1 = out + 0;
    float* o_pred2 = out + 5120;
    float* o_S     = out + 10240;
    float* o_H     = out + 665600;
    float* o_ind   = out + 9054208;
    float* o_E     = out + 9054720;
    float* o_Q     = out + 9710080;

    // ---------------- workspace arena (total ~240 MiB — proven fit; do NOT grow: round-8 crash)
    char* base = (char*)d_ws;
    size_t off = 0;
    auto alloc = [&](size_t n) -> char* {
        char* r = base + off;
        off = (off + n + 255) & ~(size_t)255;
        return r;
    };
    int*    d_off   = (int*)alloc(513 * 4);
    double* d_a     = (double*)alloc(256 * 8);
    double* d_c     = (double*)alloc(256 * 8);
    double* d_gum   = (double*)alloc(5120 * 8);
    float*  d_corr  = (float*)alloc(160 * 4);
    float*  d_cmask = (float*)alloc(512 * 16 * 4);
    float*  d_fm    = (float*)alloc(5120 * 4);
    double* psum    = (double*)alloc(2 * 512 * 128 * 8);
    double* pssq    = (double*)alloc(2 * 512 * 128 * 8);
    int*    cnt     = (int*)alloc((size_t)NN * 4);
    int*    excl    = (int*)alloc((size_t)NN * 4);
    int*    bsum    = (int*)alloc(256 * 4);
    int*    boff    = (int*)alloc(256 * 4);
    int*    rowptr  = (int*)alloc((size_t)(NN + 1) * 4);
    int*    cursor  = (int*)alloc((size_t)NN * 4);
    int*    ecol    = (int*)alloc((size_t)EE * 4);
    float*  evalv   = (float*)alloc((size_t)EE * 4);
    double* E64     = (double*)alloc((size_t)GG * 1280 * 8);

    const size_t SZ = (size_t)NN * D * 4;   // 32 MiB per f32 tensor
    float* rot0 = (float*)alloc(SZ);
    float* rot1 = (float*)alloc(SZ);
    float* rot2 = (float*)alloc(SZ);
    float* h0   = (float*)alloc(SZ);
    float* h1   = (float*)alloc(SZ);
    float* h2   = (float*)alloc(SZ);
    float* h3   = (float*)alloc(SZ);
    float* Tenc = h2;        // N x 256 f32 spans h2+h3 (dead after encoder)
    float* hid2 = rot0;      // smlp hidden reuses rot region after prop loop

    // ---------------- small precomputations
    k_off   <<<3, 256, 0, stream>>>(gi, d_off);
    k_corr  <<<1, 256, 0, stream>>>(corr_i, corr_a, d_corr);
    k_gumbel<<<20, 256, 0, stream>>>(d_gum);

    // ---------------- CSR build
    hipMemsetAsync(cnt, 0, (size_t)NN * 4, stream);
    k_hist   <<<EE / 256, 256, 0, stream>>>(W_row, cnt);
    k_scan1  <<<256, 256, 0, stream>>>(cnt, excl, bsum);
    k_scan2  <<<1, 256, 0, stream>>>(bsum, boff);
    k_scan3  <<<256, 256, 0, stream>>>(excl, boff, rowptr, cursor);
    k_scatter<<<EE / 256, 256, 0, stream>>>(W_row, W_col, W_vals, cursor, ecol, evalv);

    // ---------------- encoder (f32); 4th GEMM fuses hidden_rep[0] = 0.5*(rot0+rot1) -> h0
    k_gemm<<<dim3(2, 512), 256, 0, stream>>>(features, enc_w1,             enc_b1,       Tenc, nullptr, nullptr, NN, 256, 128, 1);
    k_gemm<<<dim3(1, 512), 256, 0, stream>>>(Tenc,     enc_w2,             enc_b2,       rot0, nullptr, nullptr, NN, 128, 256, 0);
    k_gemm<<<dim3(2, 512), 256, 0, stream>>>(features, enc_w1 + 128 * 256, enc_b1 + 256, Tenc, nullptr, nullptr, NN, 256, 128, 1);
    k_gemm<<<dim3(1, 512), 256, 0, stream>>>(Tenc,     enc_w2 + 256 * 128, enc_b2 + 128, rot1, rot0, h0,         NN, 128, 256, 0);

    // ---------------- propagation loop: blockIdx.y dual SpMM, zero extra memory.
    // p=0: (rot0,rot1)->(rot2,h2), hidden->h1
    // p=1: (rot2,h2)->(rot0,rot1), hidden->h2   (h2 read by spmm BEFORE hidden overwrites it)
    // p=2: (rot0,rot1)->(rot2,h3), hidden(rot2,h3)->h3 (in-place elementwise, same-index, safe)
    {
        float* hbuf[4] = { h0, h1, h2, h3 };
        float* curA = rot0; float* curB = rot1;
        float* nxtA[3] = { rot2, rot0, rot2 };
        float* nxtB[3] = { h2,   rot1, h3   };
        for (int p = 0; p < 3; ++p) {
            float* nA = nxtA[p];
            float* nB = nxtB[p];
            k_spmm2<<<dim3(NN / 4, 2), 256, 0, stream>>>(rowptr, ecol, evalv, curA, nA, curB, nB);
            k_bnstats2<<<dim3(512, 2), 128, 0, stream>>>(nA, nB, psum, pssq);
            k_bnfin<<<1, 256, 0, stream>>>(psum, pssq, bn_gamma, bn_beta, d_a, d_c, 2, p);
            k_hidden<<<8192, 256, 0, stream>>>((const f4*)nA, (const f4*)nB, d_a, d_c, (f4*)hbuf[1 + p]);
            curA = nA; curB = nB;
        }
    }

    // ---------------- concat MLP -> o_H, BN+relu in place
    k_concat<<<8192, 256, 0, stream>>>((const f4*)h0, (const f4*)h1, (const f4*)h2, (const f4*)h3,
                                       concat_w1, concat_b1, concat_w2, concat_b2, (f4*)o_H);
    k_bnstats2<<<dim3(512, 1), 128, 0, stream>>>(o_H, o_H, psum, pssq);
    k_bnfin<<<1, 256, 0, stream>>>(psum, pssq, bn_gamma, bn_beta, d_a, d_c, 1, 3);
    k_bnapply<<<8192, 256, 0, stream>>>((f4*)o_H, d_a, d_c);

    // ---------------- S_all
    k_gemm<<<dim3(1, 512), 256, 0, stream>>>(o_H, smlp_w1, smlp_b1, hid2, nullptr, nullptr, NN, 128, 128, 1);
    k_s<<<256, 256, 0, stream>>>(hid2, smlp_w2, smlp_b2, o_S);

    // ---------------- E_all, heads
    k_eall <<<512, 256, 0, stream>>>(o_S, o_H, d_off, o_E, E64);
    k_pred1<<<512, 64, 0, stream>>>(E64, final_w, final_b, d_gum, targets, d_corr,
                                    o_pred1, o_ind, d_cmask);
    k_q    <<<5120, 128, 0, stream>>>(o_E, proto_w1, proto_b1, proto_w2, proto_b2,
                                      d_cmask, o_Q, d_fm);
    k_pred2<<<512, 64, 0, stream>>>(E64, final_w, final_b, d_fm, o_pred2);

    (void)in_sizes; (void)n_in; (void)out_size; (void)ws_size;
}